// Round 1
// baseline (615.931 us; speedup 1.0000x reference)
//
#include <hip/hip_runtime.h>
#include <math.h>

#define N_NODES 50000
#define N_EDGES 800000
#define ET (N_EDGES + N_NODES)   // 850000 incl. self-loops
#define F_IN_DIM 128
#define HID 64
#define NG 512
#define NEG 0.2f

static __device__ __forceinline__ float wave_sum(float v) {
    for (int o = 32; o; o >>= 1) v += __shfl_xor(v, o, 64);
    return v;
}
static __device__ __forceinline__ float wave_max(float v) {
    for (int o = 32; o; o >>= 1) v = fmaxf(v, __shfl_xor(v, o, 64));
    return v;
}

// ---- mean(edge_weight) partial reduce ----
__global__ void reduce_mean_k(const float* __restrict__ ew, float* __restrict__ acc) {
    float s = 0.f;
    for (int i = blockIdx.x * blockDim.x + threadIdx.x; i < N_EDGES; i += gridDim.x * blockDim.x)
        s += ew[i];
    s = wave_sum(s);
    __shared__ float tmp[4];
    int lane = threadIdx.x & 63, wv = threadIdx.x >> 6;
    if (lane == 0) tmp[wv] = s;
    __syncthreads();
    if (threadIdx.x == 0) {
        float t = tmp[0] + tmp[1] + tmp[2] + tmp[3];
        atomicAdd(acc, t);
    }
}

// ---- finalize mean; compute ce[l] = dot(We_l, ae_l) ----
__global__ void prep_k(const float* __restrict__ acc, float* __restrict__ mean_out,
                       const float* __restrict__ We1, const float* __restrict__ ae1,
                       const float* __restrict__ We2, const float* __restrict__ ae2,
                       const float* __restrict__ We3, const float* __restrict__ ae3,
                       float* __restrict__ ce) {
    int wv = threadIdx.x >> 6, lane = threadIdx.x & 63;
    if (threadIdx.x == 0) mean_out[0] = acc[0] / (float)N_EDGES;
    if (wv < 3) {
        const float* We = (wv == 0) ? We1 : (wv == 1) ? We2 : We3;
        const float* ae = (wv == 0) ? ae1 : (wv == 1) ? ae2 : We3 == ae3 ? ae3 : ae3;
        float v = We[lane] * ae[lane];
        v = wave_sum(v);
        if (lane == 0) ce[wv] = v;
    }
}

// ---- CSR build: count in-degree ----
__global__ void count_k(const int* __restrict__ ei, int* __restrict__ counts) {
    int e = blockIdx.x * blockDim.x + threadIdx.x;
    if (e >= ET) return;
    int dst = (e < N_EDGES) ? ei[N_EDGES + e] : (e - N_EDGES);
    atomicAdd(&counts[dst], 1);
}

// ---- block-wise inclusive scan (1024/block) ----
__global__ void scan1_k(const int* __restrict__ counts, int* __restrict__ row_ptr,
                        int* __restrict__ bsums) {
    __shared__ int tmp[1024];
    int gid = blockIdx.x * 1024 + threadIdx.x;
    int v = (gid < N_NODES) ? counts[gid] : 0;
    tmp[threadIdx.x] = v;
    __syncthreads();
    for (int o = 1; o < 1024; o <<= 1) {
        int t = (threadIdx.x >= (unsigned)o) ? tmp[threadIdx.x - o] : 0;
        __syncthreads();
        tmp[threadIdx.x] += t;
        __syncthreads();
    }
    if (gid < N_NODES) row_ptr[gid + 1] = tmp[threadIdx.x];
    if (threadIdx.x == 1023) bsums[blockIdx.x] = tmp[1023];
}

__global__ void scan2_k(int* __restrict__ bsums, int nb) {
    if (blockIdx.x == 0 && threadIdx.x == 0) {
        int run = 0;
        for (int i = 0; i < nb; ++i) { int t = bsums[i]; bsums[i] = run; run += t; }
    }
}

__global__ void scan3_k(const int* __restrict__ counts, int* __restrict__ row_ptr,
                        const int* __restrict__ bsums, int* __restrict__ fill) {
    int gid = blockIdx.x * 1024 + threadIdx.x;
    if (gid >= N_NODES) return;
    int o = bsums[blockIdx.x];
    int inc = row_ptr[gid + 1] + o;
    row_ptr[gid + 1] = inc;
    fill[gid] = inc - counts[gid];
    if (gid == 0) row_ptr[0] = 0;
}

// ---- scatter edges into CSR order ----
__global__ void scatter_k(const int* __restrict__ ei, const float* __restrict__ ew,
                          const float* __restrict__ mean, int* __restrict__ fill,
                          int* __restrict__ csr_src, float* __restrict__ csr_w) {
    int e = blockIdx.x * blockDim.x + threadIdx.x;
    if (e >= ET) return;
    int src, dst; float w;
    if (e < N_EDGES) { src = ei[e]; dst = ei[N_EDGES + e]; w = ew[e]; }
    else             { src = dst = e - N_EDGES; w = mean[0]; }
    int pos = atomicAdd(&fill[dst], 1);
    csr_src[pos] = src;
    csr_w[pos] = w;
}

// ---- H = X @ W, fused a_src/a_dst; one lane per output column ----
__global__ void gemm_att_k(const float* __restrict__ X, int F,
                           const float* __restrict__ W,
                           const float* __restrict__ as_, const float* __restrict__ ad_,
                           float* __restrict__ H, float* __restrict__ Asrc,
                           float* __restrict__ Adst) {
    extern __shared__ float Ws[];
    int lane = threadIdx.x & 63, wv = threadIdx.x >> 6;
    for (int i = threadIdx.x; i < F * HID; i += blockDim.x) Ws[i] = W[i];
    __syncthreads();
    float asf = as_[lane], adf = ad_[lane];
    int row0 = blockIdx.x * 32 + wv * 8;
    for (int r = 0; r < 8; ++r) {
        int row = row0 + r;
        if (row >= N_NODES) return;
        const float4* x4 = (const float4*)(X + (size_t)row * F);
        float acc = 0.f;
        int nk4 = F >> 2;
        for (int k4 = 0; k4 < nk4; ++k4) {
            float4 xv = x4[k4];
            int k = k4 << 2;
            acc += xv.x * Ws[(k + 0) * HID + lane];
            acc += xv.y * Ws[(k + 1) * HID + lane];
            acc += xv.z * Ws[(k + 2) * HID + lane];
            acc += xv.w * Ws[(k + 3) * HID + lane];
        }
        H[(size_t)row * HID + lane] = acc;
        float vs = acc * asf, vd = acc * adf;
        for (int o = 32; o; o >>= 1) { vs += __shfl_xor(vs, o, 64); vd += __shfl_xor(vd, o, 64); }
        if (lane == 0) { Asrc[row] = vs; Adst[row] = vd; }
    }
}

// ---- per-dst-node softmax + weighted gather; one wave per node, lane = feature ----
__global__ void aggregate_k(const float* __restrict__ H, const int* __restrict__ row_ptr,
                            const int* __restrict__ csr_src, const float* __restrict__ csr_w,
                            const float* __restrict__ Asrc, const float* __restrict__ Adst,
                            const float* __restrict__ ceArr, int ci,
                            const float* __restrict__ bias, float* __restrict__ Out,
                            int do_relu) {
    int wv = threadIdx.x >> 6, lane = threadIdx.x & 63;
    int n = blockIdx.x * (blockDim.x >> 6) + wv;
    if (n >= N_NODES) return;
    int start = row_ptr[n], end = row_ptr[n + 1];
    float c = ceArr[ci];
    float ad = Adst[n];
    // pass 1: wave max of leaky(alpha)
    float lmax = -1e30f;
    for (int pos = start + lane; pos < end; pos += 64) {
        float al = Asrc[csr_src[pos]] + ad + c * csr_w[pos];
        al = (al > 0.f) ? al : NEG * al;
        lmax = fmaxf(lmax, al);
    }
    float m = wave_max(lmax);
    // pass 2: chunked exp + shuffle-broadcast feature gather
    float acc = 0.f, lsum = 0.f;
    for (int base = start; base < end; base += 64) {
        int pos = base + lane;
        int src = 0; float p = 0.f;
        if (pos < end) {
            src = csr_src[pos];
            float al = Asrc[src] + ad + c * csr_w[pos];
            al = (al > 0.f) ? al : NEG * al;
            p = __expf(al - m);
            lsum += p;
        }
        int cnt = min(64, end - base);
        for (int j = 0; j < cnt; ++j) {
            float pj = __shfl(p, j, 64);
            int   sj = __shfl(src, j, 64);
            acc += pj * H[(size_t)sj * HID + lane];
        }
    }
    float s = wave_sum(lsum);
    acc = acc / (s + 1e-16f) + bias[lane];
    if (do_relu) acc = fmaxf(acc, 0.f);
    Out[(size_t)n * HID + lane] = acc;
}

// ---- mean pool (batch sorted): chunked register accumulate, flush on boundary ----
__global__ void pool_k(const float* __restrict__ act, const int* __restrict__ batch,
                       float* __restrict__ sums, float* __restrict__ cnt) {
    int wv = threadIdx.x >> 6, lane = threadIdx.x & 63;
    int wid = blockIdx.x * (blockDim.x >> 6) + wv;
    const int CHUNK = 64;
    int base = wid * CHUNK;
    if (base >= N_NODES) return;
    int end = min(base + CHUNK, N_NODES);
    float acc = 0.f;
    int cur = batch[base], cl = 0;
    for (int n = base; n < end; ++n) {
        int g = batch[n];
        if (g != cur) {
            atomicAdd(&sums[(size_t)cur * HID + lane], acc);
            if (lane == 0) atomicAdd(&cnt[cur], (float)cl);
            acc = 0.f; cl = 0; cur = g;
        }
        acc += act[(size_t)n * HID + lane];
        cl++;
    }
    atomicAdd(&sums[(size_t)cur * HID + lane], acc);
    if (lane == 0) atomicAdd(&cnt[cur], (float)cl);
}

// ---- readout: mean, linear, sigmoid ----
__global__ void readout_k(const float* __restrict__ sums, const float* __restrict__ cnt,
                          const float* __restrict__ lin_w, const float* __restrict__ lin_b,
                          float* __restrict__ out) {
    int wv = threadIdx.x >> 6, lane = threadIdx.x & 63;
    int g = blockIdx.x * 4 + wv;
    if (g >= NG) return;
    float c = fmaxf(cnt[g], 1.f);
    float v = sums[(size_t)g * HID + lane] / c * lin_w[lane];
    v = wave_sum(v);
    if (lane == 0) {
        float z = v + lin_b[0];
        out[g] = 1.f / (1.f + __expf(-z));
    }
}

extern "C" void kernel_launch(void* const* d_in, const int* in_sizes, int n_in,
                              void* d_out, int out_size, void* d_ws, size_t ws_size,
                              hipStream_t stream) {
    const float* x     = (const float*)d_in[0];
    const int*   ei    = (const int*)d_in[1];
    const float* ew    = (const float*)d_in[2];
    const int*   batch = (const int*)d_in[3];
    const float* W1  = (const float*)d_in[4];
    const float* as1 = (const float*)d_in[5];
    const float* ad1 = (const float*)d_in[6];
    const float* We1 = (const float*)d_in[7];
    const float* ae1 = (const float*)d_in[8];
    const float* b1  = (const float*)d_in[9];
    const float* W2  = (const float*)d_in[10];
    const float* as2 = (const float*)d_in[11];
    const float* ad2 = (const float*)d_in[12];
    const float* We2 = (const float*)d_in[13];
    const float* ae2 = (const float*)d_in[14];
    const float* b2  = (const float*)d_in[15];
    const float* W3  = (const float*)d_in[16];
    const float* as3 = (const float*)d_in[17];
    const float* ad3 = (const float*)d_in[18];
    const float* We3 = (const float*)d_in[19];
    const float* ae3 = (const float*)d_in[20];
    const float* b3  = (const float*)d_in[21];
    const float* lin_w = (const float*)d_in[22];
    const float* lin_b = (const float*)d_in[23];
    float* out = (float*)d_out;

    char* w = (char*)d_ws;
    size_t off = 0;
    auto alloc = [&](size_t bytes) -> void* {
        void* p = w + off;
        off = (off + bytes + 255) & ~(size_t)255;
        return p;
    };
    // zeroed region (memset each call; ws is poisoned)
    int*   counts   = (int*)alloc(N_NODES * sizeof(int));
    float* mean_acc = (float*)alloc(sizeof(float));
    float* cnt_g    = (float*)alloc(NG * sizeof(float));
    float* sums_g   = (float*)alloc((size_t)NG * HID * sizeof(float));
    size_t zero_bytes = off;
    // non-zeroed
    float* ce      = (float*)alloc(4 * sizeof(float));
    float* mean    = (float*)alloc(sizeof(float));
    int*   row_ptr = (int*)alloc((N_NODES + 1) * sizeof(int));
    int*   fill    = (int*)alloc(N_NODES * sizeof(int));
    int*   bsums   = (int*)alloc(64 * sizeof(int));
    int*   csr_src = (int*)alloc((size_t)ET * sizeof(int));
    float* csr_w   = (float*)alloc((size_t)ET * sizeof(float));
    float* a_src   = (float*)alloc(N_NODES * sizeof(float));
    float* a_dst   = (float*)alloc(N_NODES * sizeof(float));
    float* hbuf    = (float*)alloc((size_t)N_NODES * HID * sizeof(float));
    float* actA    = (float*)alloc((size_t)N_NODES * HID * sizeof(float));
    float* actB    = (float*)alloc((size_t)N_NODES * HID * sizeof(float));

    hipMemsetAsync(d_ws, 0, zero_bytes, stream);

    reduce_mean_k<<<256, 256, 0, stream>>>(ew, mean_acc);
    prep_k<<<1, 256, 0, stream>>>(mean_acc, mean, We1, ae1, We2, ae2, We3, ae3, ce);

    int egrid = (ET + 255) / 256;
    count_k<<<egrid, 256, 0, stream>>>(ei, counts);
    int sgrid = (N_NODES + 1023) / 1024;  // 49
    scan1_k<<<sgrid, 1024, 0, stream>>>(counts, row_ptr, bsums);
    scan2_k<<<1, 64, 0, stream>>>(bsums, sgrid);
    scan3_k<<<sgrid, 1024, 0, stream>>>(counts, row_ptr, bsums, fill);
    scatter_k<<<egrid, 256, 0, stream>>>(ei, ew, mean, fill, csr_src, csr_w);

    int ggrid = (N_NODES + 31) / 32;   // 32 rows/block
    int agrid = (N_NODES + 3) / 4;     // 4 waves/block

    // layer 1
    gemm_att_k<<<ggrid, 256, F_IN_DIM * HID * sizeof(float), stream>>>(
        x, F_IN_DIM, W1, as1, ad1, hbuf, a_src, a_dst);
    aggregate_k<<<agrid, 256, 0, stream>>>(hbuf, row_ptr, csr_src, csr_w,
                                           a_src, a_dst, ce, 0, b1, actA, 1);
    // layer 2
    gemm_att_k<<<ggrid, 256, HID * HID * sizeof(float), stream>>>(
        actA, HID, W2, as2, ad2, hbuf, a_src, a_dst);
    aggregate_k<<<agrid, 256, 0, stream>>>(hbuf, row_ptr, csr_src, csr_w,
                                           a_src, a_dst, ce, 1, b2, actB, 1);
    // layer 3
    gemm_att_k<<<ggrid, 256, HID * HID * sizeof(float), stream>>>(
        actB, HID, W3, as3, ad3, hbuf, a_src, a_dst);
    aggregate_k<<<agrid, 256, 0, stream>>>(hbuf, row_ptr, csr_src, csr_w,
                                           a_src, a_dst, ce, 2, b3, actA, 0);

    // pool + readout
    int pgrid = ((N_NODES + 63) / 64 + 3) / 4;
    pool_k<<<pgrid, 256, 0, stream>>>(actA, batch, sums_g, cnt_g);
    readout_k<<<NG / 4, 256, 0, stream>>>(sums_g, cnt_g, lin_w, lin_b, out);
}

// Round 2
// 501.670 us; speedup vs baseline: 1.2278x; 1.2278x over previous
//
#include <hip/hip_runtime.h>
#include <math.h>

#define N_NODES 50000
#define N_EDGES 800000
#define ET (N_EDGES + N_NODES)   // 850000 incl. self-loops
#define F_IN_DIM 128
#define HID 64
#define NG 512
#define NEG 0.2f

static __device__ __forceinline__ float wave_sum(float v) {
    for (int o = 32; o; o >>= 1) v += __shfl_xor(v, o, 64);
    return v;
}
static __device__ __forceinline__ float wave_max(float v) {
    for (int o = 32; o; o >>= 1) v = fmaxf(v, __shfl_xor(v, o, 64));
    return v;
}

// ---- mean(edge_weight) partial reduce ----
__global__ void reduce_mean_k(const float* __restrict__ ew, float* __restrict__ acc) {
    float s = 0.f;
    for (int i = blockIdx.x * blockDim.x + threadIdx.x; i < N_EDGES; i += gridDim.x * blockDim.x)
        s += ew[i];
    s = wave_sum(s);
    __shared__ float tmp[4];
    int lane = threadIdx.x & 63, wv = threadIdx.x >> 6;
    if (lane == 0) tmp[wv] = s;
    __syncthreads();
    if (threadIdx.x == 0) {
        float t = tmp[0] + tmp[1] + tmp[2] + tmp[3];
        atomicAdd(acc, t);
    }
}

// ---- finalize mean; compute ce[l] = dot(We_l, ae_l) ----
__global__ void prep_k(const float* __restrict__ acc, float* __restrict__ mean_out,
                       const float* __restrict__ We1, const float* __restrict__ ae1,
                       const float* __restrict__ We2, const float* __restrict__ ae2,
                       const float* __restrict__ We3, const float* __restrict__ ae3,
                       float* __restrict__ ce) {
    int wv = threadIdx.x >> 6, lane = threadIdx.x & 63;
    if (threadIdx.x == 0) mean_out[0] = acc[0] / (float)N_EDGES;
    if (wv < 3) {
        const float* We = (wv == 0) ? We1 : (wv == 1) ? We2 : We3;
        const float* ae = (wv == 0) ? ae1 : (wv == 1) ? ae2 : ae3;
        float v = We[lane] * ae[lane];
        v = wave_sum(v);
        if (lane == 0) ce[wv] = v;
    }
}

// ---- CSR build: count in-degree ----
__global__ void count_k(const int* __restrict__ ei, int* __restrict__ counts) {
    int e = blockIdx.x * blockDim.x + threadIdx.x;
    if (e >= ET) return;
    int dst = (e < N_EDGES) ? ei[N_EDGES + e] : (e - N_EDGES);
    atomicAdd(&counts[dst], 1);
}

// ---- block-wise inclusive scan (1024/block) ----
__global__ void scan1_k(const int* __restrict__ counts, int* __restrict__ row_ptr,
                        int* __restrict__ bsums) {
    __shared__ int tmp[1024];
    int gid = blockIdx.x * 1024 + threadIdx.x;
    int v = (gid < N_NODES) ? counts[gid] : 0;
    tmp[threadIdx.x] = v;
    __syncthreads();
    for (int o = 1; o < 1024; o <<= 1) {
        int t = (threadIdx.x >= (unsigned)o) ? tmp[threadIdx.x - o] : 0;
        __syncthreads();
        tmp[threadIdx.x] += t;
        __syncthreads();
    }
    if (gid < N_NODES) row_ptr[gid + 1] = tmp[threadIdx.x];
    if (threadIdx.x == 1023) bsums[blockIdx.x] = tmp[1023];
}

__global__ void scan2_k(int* __restrict__ bsums, int nb) {
    if (blockIdx.x == 0 && threadIdx.x == 0) {
        int run = 0;
        for (int i = 0; i < nb; ++i) { int t = bsums[i]; bsums[i] = run; run += t; }
    }
}

__global__ void scan3_k(const int* __restrict__ counts, int* __restrict__ row_ptr,
                        const int* __restrict__ bsums, int* __restrict__ fill) {
    int gid = blockIdx.x * 1024 + threadIdx.x;
    if (gid >= N_NODES) return;
    int o = bsums[blockIdx.x];
    int inc = row_ptr[gid + 1] + o;
    row_ptr[gid + 1] = inc;
    fill[gid] = inc - counts[gid];
    if (gid == 0) row_ptr[0] = 0;
}

// ---- scatter edges into CSR order ----
__global__ void scatter_k(const int* __restrict__ ei, const float* __restrict__ ew,
                          const float* __restrict__ mean, int* __restrict__ fill,
                          int* __restrict__ csr_src, float* __restrict__ csr_w) {
    int e = blockIdx.x * blockDim.x + threadIdx.x;
    if (e >= ET) return;
    int src, dst; float w;
    if (e < N_EDGES) { src = ei[e]; dst = ei[N_EDGES + e]; w = ew[e]; }
    else             { src = dst = e - N_EDGES; w = mean[0]; }
    int pos = atomicAdd(&fill[dst], 1);
    csr_src[pos] = src;
    csr_w[pos] = w;
}

// ---- H = X @ W (register-tiled), fused a_src/a_dst ----
// block = 256 threads -> 64 rows x 64 cols tile; thread = 4x4 register tile.
// tx = tid & 15 (col quad: cols tx*4..tx*4+3), ty = tid >> 4 (row quad).
// W fully LDS-resident [F x 64]; X staged in 64x16 tiles (stride 17 pad).
__global__ __launch_bounds__(256) void gemm_att_k(
        const float* __restrict__ X, int F,
        const float* __restrict__ W,
        const float* __restrict__ as_, const float* __restrict__ ad_,
        float* __restrict__ H, float* __restrict__ Asrc,
        float* __restrict__ Adst) {
    extern __shared__ float smem[];
    float* Ws = smem;               // F*64 floats
    float* Xs = smem + F * HID;     // 64*17 floats
    const int tid = threadIdx.x;
    const int tx = tid & 15, ty = tid >> 4;
    const int rowBase = blockIdx.x * 64;

    // stage W (coalesced float4)
    {
        const float4* W4 = (const float4*)W;
        float4* Ws4 = (float4*)Ws;
        int n4 = (F * HID) >> 2;
        for (int i = tid; i < n4; i += 256) Ws4[i] = W4[i];
    }

    float4 acc0 = {0,0,0,0}, acc1 = {0,0,0,0}, acc2 = {0,0,0,0}, acc3 = {0,0,0,0};

    const int xrow = tid >> 2;          // 0..63: row within tile to stage
    const int xkq  = tid & 3;           // which float4 of the 16-k slab
    const int nkt = F >> 4;             // k-tiles of 16

    for (int kt = 0; kt < nkt; ++kt) {
        __syncthreads();                // Ws ready (first iter) / prior reads done
        int k0 = kt << 4;
        int grow = rowBase + xrow;
        float4 xv = {0,0,0,0};
        if (grow < N_NODES)
            xv = *(const float4*)(X + (size_t)grow * F + k0 + (xkq << 2));
        float* xd = Xs + xrow * 17 + (xkq << 2);
        xd[0] = xv.x; xd[1] = xv.y; xd[2] = xv.z; xd[3] = xv.w;
        __syncthreads();

        #pragma unroll
        for (int kk = 0; kk < 16; ++kk) {
            float4 b = *(const float4*)&Ws[(k0 + kk) * HID + (tx << 2)];
            float a0 = Xs[(ty * 4 + 0) * 17 + kk];
            float a1 = Xs[(ty * 4 + 1) * 17 + kk];
            float a2 = Xs[(ty * 4 + 2) * 17 + kk];
            float a3 = Xs[(ty * 4 + 3) * 17 + kk];
            acc0.x += a0 * b.x; acc0.y += a0 * b.y; acc0.z += a0 * b.z; acc0.w += a0 * b.w;
            acc1.x += a1 * b.x; acc1.y += a1 * b.y; acc1.z += a1 * b.z; acc1.w += a1 * b.w;
            acc2.x += a2 * b.x; acc2.y += a2 * b.y; acc2.z += a2 * b.z; acc2.w += a2 * b.w;
            acc3.x += a3 * b.x; acc3.y += a3 * b.y; acc3.z += a3 * b.z; acc3.w += a3 * b.w;
        }
    }

    // epilogue: store H rows, fused attention dots
    float4 as4 = *(const float4*)(as_ + (tx << 2));
    float4 ad4 = *(const float4*)(ad_ + (tx << 2));
    float4 accs[4] = {acc0, acc1, acc2, acc3};
    #pragma unroll
    for (int i = 0; i < 4; ++i) {
        int row = rowBase + ty * 4 + i;
        if (row >= N_NODES) break;
        float4 a = accs[i];
        *(float4*)(H + (size_t)row * HID + (tx << 2)) = a;
        float vs = a.x * as4.x + a.y * as4.y + a.z * as4.z + a.w * as4.w;
        float vd = a.x * ad4.x + a.y * ad4.y + a.z * ad4.z + a.w * ad4.w;
        #pragma unroll
        for (int o = 8; o; o >>= 1) { vs += __shfl_xor(vs, o, 64); vd += __shfl_xor(vd, o, 64); }
        if (tx == 0) { Asrc[row] = vs; Adst[row] = vd; }
    }
}

// ---- per-dst-node softmax + weighted gather; one wave per node, lane = feature ----
__global__ void aggregate_k(const float* __restrict__ H, const int* __restrict__ row_ptr,
                            const int* __restrict__ csr_src, const float* __restrict__ csr_w,
                            const float* __restrict__ Asrc, const float* __restrict__ Adst,
                            const float* __restrict__ ceArr, int ci,
                            const float* __restrict__ bias, float* __restrict__ Out,
                            int do_relu) {
    int wv = threadIdx.x >> 6, lane = threadIdx.x & 63;
    int n = blockIdx.x * (blockDim.x >> 6) + wv;
    if (n >= N_NODES) return;
    int start = row_ptr[n], end = row_ptr[n + 1];
    float c = ceArr[ci];
    float ad = Adst[n];
    // pass 1: wave max of leaky(alpha)
    float lmax = -1e30f;
    for (int pos = start + lane; pos < end; pos += 64) {
        float al = Asrc[csr_src[pos]] + ad + c * csr_w[pos];
        al = (al > 0.f) ? al : NEG * al;
        lmax = fmaxf(lmax, al);
    }
    float m = wave_max(lmax);
    // pass 2: chunked exp + shuffle-broadcast feature gather
    float acc = 0.f, lsum = 0.f;
    for (int base = start; base < end; base += 64) {
        int pos = base + lane;
        int src = 0; float p = 0.f;
        if (pos < end) {
            src = csr_src[pos];
            float al = Asrc[src] + ad + c * csr_w[pos];
            al = (al > 0.f) ? al : NEG * al;
            p = __expf(al - m);
            lsum += p;
        }
        int cnt = min(64, end - base);
        for (int j = 0; j < cnt; ++j) {
            float pj = __shfl(p, j, 64);
            int   sj = __shfl(src, j, 64);
            acc += pj * H[(size_t)sj * HID + lane];
        }
    }
    float s = wave_sum(lsum);
    acc = acc / (s + 1e-16f) + bias[lane];
    if (do_relu) acc = fmaxf(acc, 0.f);
    Out[(size_t)n * HID + lane] = acc;
}

// ---- mean pool (batch sorted): chunked register accumulate, flush on boundary ----
__global__ void pool_k(const float* __restrict__ act, const int* __restrict__ batch,
                       float* __restrict__ sums, float* __restrict__ cnt) {
    int wv = threadIdx.x >> 6, lane = threadIdx.x & 63;
    int wid = blockIdx.x * (blockDim.x >> 6) + wv;
    const int CHUNK = 64;
    int base = wid * CHUNK;
    if (base >= N_NODES) return;
    int end = min(base + CHUNK, N_NODES);
    float acc = 0.f;
    int cur = batch[base], cl = 0;
    for (int n = base; n < end; ++n) {
        int g = batch[n];
        if (g != cur) {
            atomicAdd(&sums[(size_t)cur * HID + lane], acc);
            if (lane == 0) atomicAdd(&cnt[cur], (float)cl);
            acc = 0.f; cl = 0; cur = g;
        }
        acc += act[(size_t)n * HID + lane];
        cl++;
    }
    atomicAdd(&sums[(size_t)cur * HID + lane], acc);
    if (lane == 0) atomicAdd(&cnt[cur], (float)cl);
}

// ---- readout: mean, linear, sigmoid ----
__global__ void readout_k(const float* __restrict__ sums, const float* __restrict__ cnt,
                          const float* __restrict__ lin_w, const float* __restrict__ lin_b,
                          float* __restrict__ out) {
    int wv = threadIdx.x >> 6, lane = threadIdx.x & 63;
    int g = blockIdx.x * 4 + wv;
    if (g >= NG) return;
    float c = fmaxf(cnt[g], 1.f);
    float v = sums[(size_t)g * HID + lane] / c * lin_w[lane];
    v = wave_sum(v);
    if (lane == 0) {
        float z = v + lin_b[0];
        out[g] = 1.f / (1.f + __expf(-z));
    }
}

extern "C" void kernel_launch(void* const* d_in, const int* in_sizes, int n_in,
                              void* d_out, int out_size, void* d_ws, size_t ws_size,
                              hipStream_t stream) {
    const float* x     = (const float*)d_in[0];
    const int*   ei    = (const int*)d_in[1];
    const float* ew    = (const float*)d_in[2];
    const int*   batch = (const int*)d_in[3];
    const float* W1  = (const float*)d_in[4];
    const float* as1 = (const float*)d_in[5];
    const float* ad1 = (const float*)d_in[6];
    const float* We1 = (const float*)d_in[7];
    const float* ae1 = (const float*)d_in[8];
    const float* b1  = (const float*)d_in[9];
    const float* W2  = (const float*)d_in[10];
    const float* as2 = (const float*)d_in[11];
    const float* ad2 = (const float*)d_in[12];
    const float* We2 = (const float*)d_in[13];
    const float* ae2 = (const float*)d_in[14];
    const float* b2  = (const float*)d_in[15];
    const float* W3  = (const float*)d_in[16];
    const float* as3 = (const float*)d_in[17];
    const float* ad3 = (const float*)d_in[18];
    const float* We3 = (const float*)d_in[19];
    const float* ae3 = (const float*)d_in[20];
    const float* b3  = (const float*)d_in[21];
    const float* lin_w = (const float*)d_in[22];
    const float* lin_b = (const float*)d_in[23];
    float* out = (float*)d_out;

    char* w = (char*)d_ws;
    size_t off = 0;
    auto alloc = [&](size_t bytes) -> void* {
        void* p = w + off;
        off = (off + bytes + 255) & ~(size_t)255;
        return p;
    };
    // zeroed region (memset each call; ws is poisoned)
    int*   counts   = (int*)alloc(N_NODES * sizeof(int));
    float* mean_acc = (float*)alloc(sizeof(float));
    float* cnt_g    = (float*)alloc(NG * sizeof(float));
    float* sums_g   = (float*)alloc((size_t)NG * HID * sizeof(float));
    size_t zero_bytes = off;
    // non-zeroed
    float* ce      = (float*)alloc(4 * sizeof(float));
    float* mean    = (float*)alloc(sizeof(float));
    int*   row_ptr = (int*)alloc((N_NODES + 1) * sizeof(int));
    int*   fill    = (int*)alloc(N_NODES * sizeof(int));
    int*   bsums   = (int*)alloc(64 * sizeof(int));
    int*   csr_src = (int*)alloc((size_t)ET * sizeof(int));
    float* csr_w   = (float*)alloc((size_t)ET * sizeof(float));
    float* a_src   = (float*)alloc(N_NODES * sizeof(float));
    float* a_dst   = (float*)alloc(N_NODES * sizeof(float));
    float* hbuf    = (float*)alloc((size_t)N_NODES * HID * sizeof(float));
    float* actA    = (float*)alloc((size_t)N_NODES * HID * sizeof(float));
    float* actB    = (float*)alloc((size_t)N_NODES * HID * sizeof(float));

    hipMemsetAsync(d_ws, 0, zero_bytes, stream);

    reduce_mean_k<<<256, 256, 0, stream>>>(ew, mean_acc);
    prep_k<<<1, 256, 0, stream>>>(mean_acc, mean, We1, ae1, We2, ae2, We3, ae3, ce);

    int egrid = (ET + 255) / 256;
    count_k<<<egrid, 256, 0, stream>>>(ei, counts);
    int sgrid = (N_NODES + 1023) / 1024;  // 49
    scan1_k<<<sgrid, 1024, 0, stream>>>(counts, row_ptr, bsums);
    scan2_k<<<1, 64, 0, stream>>>(bsums, sgrid);
    scan3_k<<<sgrid, 1024, 0, stream>>>(counts, row_ptr, bsums, fill);
    scatter_k<<<egrid, 256, 0, stream>>>(ei, ew, mean, fill, csr_src, csr_w);

    int ggrid = (N_NODES + 63) / 64;   // 64 rows/block
    int agrid = (N_NODES + 3) / 4;     // 4 waves/block

    size_t lds1 = (size_t)(F_IN_DIM * HID + 64 * 17) * sizeof(float);
    size_t lds2 = (size_t)(HID * HID + 64 * 17) * sizeof(float);

    // layer 1
    gemm_att_k<<<ggrid, 256, lds1, stream>>>(x, F_IN_DIM, W1, as1, ad1, hbuf, a_src, a_dst);
    aggregate_k<<<agrid, 256, 0, stream>>>(hbuf, row_ptr, csr_src, csr_w,
                                           a_src, a_dst, ce, 0, b1, actA, 1);
    // layer 2
    gemm_att_k<<<ggrid, 256, lds2, stream>>>(actA, HID, W2, as2, ad2, hbuf, a_src, a_dst);
    aggregate_k<<<agrid, 256, 0, stream>>>(hbuf, row_ptr, csr_src, csr_w,
                                           a_src, a_dst, ce, 1, b2, actB, 1);
    // layer 3
    gemm_att_k<<<ggrid, 256, lds2, stream>>>(actB, HID, W3, as3, ad3, hbuf, a_src, a_dst);
    aggregate_k<<<agrid, 256, 0, stream>>>(hbuf, row_ptr, csr_src, csr_w,
                                           a_src, a_dst, ce, 2, b3, actA, 0);

    // pool + readout
    int pgrid = ((N_NODES + 63) / 64 + 3) / 4;
    pool_k<<<pgrid, 256, 0, stream>>>(actA, batch, sums_g, cnt_g);
    readout_k<<<NG / 4, 256, 0, stream>>>(sums_g, cnt_g, lin_w, lin_b, out);
}

// Round 3
// 399.391 us; speedup vs baseline: 1.5422x; 1.2561x over previous
//
#include <hip/hip_runtime.h>
#include <math.h>

#define N_NODES 50000
#define N_EDGES 800000
#define ET (N_EDGES + N_NODES)   // 850000 incl. self-loops
#define F_IN_DIM 128
#define HID 64
#define NG 512
#define NEG 0.2f

static __device__ __forceinline__ float wave_sum(float v) {
    for (int o = 32; o; o >>= 1) v += __shfl_xor(v, o, 64);
    return v;
}
static __device__ __forceinline__ float wave_max(float v) {
    for (int o = 32; o; o >>= 1) v = fmaxf(v, __shfl_xor(v, o, 64));
    return v;
}

// ---- fused: in-degree count + mean(edge_weight) partial reduce ----
__global__ void edge_prep_k(const int* __restrict__ ei, const float* __restrict__ ew,
                            int* __restrict__ counts, float* __restrict__ mean_acc) {
    int e = blockIdx.x * blockDim.x + threadIdx.x;
    float s = 0.f;
    if (e < ET) {
        int dst;
        if (e < N_EDGES) { dst = ei[N_EDGES + e]; s = ew[e]; }
        else             { dst = e - N_EDGES; }
        atomicAdd(&counts[dst], 1);
    }
    s = wave_sum(s);
    __shared__ float tmp[4];
    int lane = threadIdx.x & 63, wv = threadIdx.x >> 6;
    if (lane == 0) tmp[wv] = s;
    __syncthreads();
    if (threadIdx.x == 0) atomicAdd(mean_acc, tmp[0] + tmp[1] + tmp[2] + tmp[3]);
}

// ---- block-wise inclusive scan (1024/block) ----
__global__ void scan1_k(const int* __restrict__ counts, int* __restrict__ row_ptr,
                        int* __restrict__ bsums) {
    __shared__ int tmp[1024];
    int gid = blockIdx.x * 1024 + threadIdx.x;
    int v = (gid < N_NODES) ? counts[gid] : 0;
    tmp[threadIdx.x] = v;
    __syncthreads();
    for (int o = 1; o < 1024; o <<= 1) {
        int t = (threadIdx.x >= (unsigned)o) ? tmp[threadIdx.x - o] : 0;
        __syncthreads();
        tmp[threadIdx.x] += t;
        __syncthreads();
    }
    if (gid < N_NODES) row_ptr[gid + 1] = tmp[threadIdx.x];
    if (threadIdx.x == 1023) bsums[blockIdx.x] = tmp[1023];
}

// ---- fused: wave-scan of block sums + mean finalize + ce[l]=dot(We_l,ae_l) ----
__global__ void small_k(int* __restrict__ bsums, int nb,
                        const float* __restrict__ acc, float* __restrict__ mean_out,
                        const float* __restrict__ We1, const float* __restrict__ ae1,
                        const float* __restrict__ We2, const float* __restrict__ ae2,
                        const float* __restrict__ We3, const float* __restrict__ ae3,
                        float* __restrict__ ce) {
    int wv = threadIdx.x >> 6, lane = threadIdx.x & 63;
    if (wv == 0) {
        int orig = (lane < nb) ? bsums[lane] : 0;
        int v = orig;
        #pragma unroll
        for (int o = 1; o < 64; o <<= 1) {
            int t = __shfl_up(v, o, 64);
            if (lane >= o) v += t;
        }
        if (lane < nb) bsums[lane] = v - orig;   // exclusive
        if (lane == 63) mean_out[0] = acc[0] / (float)N_EDGES;
    } else {
        const float* We = (wv == 1) ? We1 : (wv == 2) ? We2 : We3;
        const float* ae = (wv == 1) ? ae1 : (wv == 2) ? ae2 : ae3;
        float v = We[lane] * ae[lane];
        v = wave_sum(v);
        if (lane == 0) ce[wv - 1] = v;
    }
}

__global__ void scan3_k(const int* __restrict__ counts, int* __restrict__ row_ptr,
                        const int* __restrict__ bsums, int* __restrict__ fill) {
    int gid = blockIdx.x * 1024 + threadIdx.x;
    if (gid >= N_NODES) return;
    int o = bsums[blockIdx.x];
    int inc = row_ptr[gid + 1] + o;
    row_ptr[gid + 1] = inc;
    fill[gid] = inc - counts[gid];
    if (gid == 0) row_ptr[0] = 0;
}

// ---- scatter edges into CSR order, interleaved (src, w) pairs ----
__global__ void scatter_k(const int* __restrict__ ei, const float* __restrict__ ew,
                          const float* __restrict__ mean, int* __restrict__ fill,
                          int2* __restrict__ csr) {
    int e = blockIdx.x * blockDim.x + threadIdx.x;
    if (e >= ET) return;
    int src, dst; float w;
    if (e < N_EDGES) { src = ei[e]; dst = ei[N_EDGES + e]; w = ew[e]; }
    else             { src = dst = e - N_EDGES; w = mean[0]; }
    int pos = atomicAdd(&fill[dst], 1);
    csr[pos] = make_int2(src, __float_as_int(w));
}

// ---- H = X @ W (register-tiled), fused a_src/a_dst ----
__global__ __launch_bounds__(256) void gemm_att_k(
        const float* __restrict__ X, int F,
        const float* __restrict__ W,
        const float* __restrict__ as_, const float* __restrict__ ad_,
        float* __restrict__ H, float* __restrict__ Asrc,
        float* __restrict__ Adst) {
    extern __shared__ float smem[];
    float* Ws = smem;               // F*64 floats
    float* Xs = smem + F * HID;     // 64*17 floats
    const int tid = threadIdx.x;
    const int tx = tid & 15, ty = tid >> 4;
    const int rowBase = blockIdx.x * 64;

    {
        const float4* W4 = (const float4*)W;
        float4* Ws4 = (float4*)Ws;
        int n4 = (F * HID) >> 2;
        for (int i = tid; i < n4; i += 256) Ws4[i] = W4[i];
    }

    float4 acc0 = {0,0,0,0}, acc1 = {0,0,0,0}, acc2 = {0,0,0,0}, acc3 = {0,0,0,0};

    const int xrow = tid >> 2;
    const int xkq  = tid & 3;
    const int nkt = F >> 4;

    for (int kt = 0; kt < nkt; ++kt) {
        __syncthreads();
        int k0 = kt << 4;
        int grow = rowBase + xrow;
        float4 xv = {0,0,0,0};
        if (grow < N_NODES)
            xv = *(const float4*)(X + (size_t)grow * F + k0 + (xkq << 2));
        float* xd = Xs + xrow * 17 + (xkq << 2);
        xd[0] = xv.x; xd[1] = xv.y; xd[2] = xv.z; xd[3] = xv.w;
        __syncthreads();

        #pragma unroll
        for (int kk = 0; kk < 16; ++kk) {
            float4 b = *(const float4*)&Ws[(k0 + kk) * HID + (tx << 2)];
            float a0 = Xs[(ty * 4 + 0) * 17 + kk];
            float a1 = Xs[(ty * 4 + 1) * 17 + kk];
            float a2 = Xs[(ty * 4 + 2) * 17 + kk];
            float a3 = Xs[(ty * 4 + 3) * 17 + kk];
            acc0.x += a0 * b.x; acc0.y += a0 * b.y; acc0.z += a0 * b.z; acc0.w += a0 * b.w;
            acc1.x += a1 * b.x; acc1.y += a1 * b.y; acc1.z += a1 * b.z; acc1.w += a1 * b.w;
            acc2.x += a2 * b.x; acc2.y += a2 * b.y; acc2.z += a2 * b.z; acc2.w += a2 * b.w;
            acc3.x += a3 * b.x; acc3.y += a3 * b.y; acc3.z += a3 * b.z; acc3.w += a3 * b.w;
        }
    }

    float4 as4 = *(const float4*)(as_ + (tx << 2));
    float4 ad4 = *(const float4*)(ad_ + (tx << 2));
    float4 accs[4] = {acc0, acc1, acc2, acc3};
    #pragma unroll
    for (int i = 0; i < 4; ++i) {
        int row = rowBase + ty * 4 + i;
        if (row >= N_NODES) break;
        float4 a = accs[i];
        *(float4*)(H + (size_t)row * HID + (tx << 2)) = a;
        float vs = a.x * as4.x + a.y * as4.y + a.z * as4.z + a.w * as4.w;
        float vd = a.x * ad4.x + a.y * ad4.y + a.z * ad4.z + a.w * ad4.w;
        #pragma unroll
        for (int o = 8; o; o >>= 1) { vs += __shfl_xor(vs, o, 64); vd += __shfl_xor(vd, o, 64); }
        if (tx == 0) { Asrc[row] = vs; Adst[row] = vd; }
    }
}

// ---- per-dst-node softmax + weighted gather; one wave per node, lane = feature ----
// Fast path (deg<=64): alpha in registers, (p,src) via wave-private LDS,
// gather with 8 independent H-row loads per waitcnt.
__global__ __launch_bounds__(256) void aggregate_k(
        const float* __restrict__ H, const int* __restrict__ row_ptr,
        const int2* __restrict__ csr,
        const float* __restrict__ Asrc, const float* __restrict__ Adst,
        const float* __restrict__ ceArr, int ci,
        const float* __restrict__ bias, float* __restrict__ Out,
        int do_relu) {
    __shared__ float lp[4][64];
    __shared__ int   ls[4][64];
    int wv = threadIdx.x >> 6, lane = threadIdx.x & 63;
    int n = blockIdx.x * 4 + wv;
    if (n >= N_NODES) return;
    int start = row_ptr[n], end = row_ptr[n + 1];
    int deg = end - start;
    float c = ceArr[ci];
    float ad = Adst[n];
    float acc = 0.f, denom;

    if (deg <= 64) {
        float al = -1e30f; int src = 0; float p = 0.f;
        if (lane < deg) {
            int2 e = csr[start + lane];
            src = e.x;
            float wgt = __int_as_float(e.y);
            al = Asrc[src] + ad + c * wgt;
            al = (al > 0.f) ? al : NEG * al;
        }
        float m = wave_max(al);
        if (lane < deg) p = __expf(al - m);
        denom = wave_sum(p);
        lp[wv][lane] = p;
        ls[wv][lane] = src;
        __builtin_amdgcn_wave_barrier();   // keep write->read order (wave-synchronous)
        int j = 0;
        for (; j + 8 <= deg; j += 8) {
            float4 p0 = *(float4*)&lp[wv][j];
            float4 p1 = *(float4*)&lp[wv][j + 4];
            int4 s0 = *(int4*)&ls[wv][j];
            int4 s1 = *(int4*)&ls[wv][j + 4];
            float v0 = H[(size_t)s0.x * HID + lane];
            float v1 = H[(size_t)s0.y * HID + lane];
            float v2 = H[(size_t)s0.z * HID + lane];
            float v3 = H[(size_t)s0.w * HID + lane];
            float v4 = H[(size_t)s1.x * HID + lane];
            float v5 = H[(size_t)s1.y * HID + lane];
            float v6 = H[(size_t)s1.z * HID + lane];
            float v7 = H[(size_t)s1.w * HID + lane];
            acc += p0.x * v0 + p0.y * v1 + p0.z * v2 + p0.w * v3
                 + p1.x * v4 + p1.y * v5 + p1.z * v6 + p1.w * v7;
        }
        for (; j + 4 <= deg; j += 4) {
            float4 p0 = *(float4*)&lp[wv][j];
            int4 s0 = *(int4*)&ls[wv][j];
            float v0 = H[(size_t)s0.x * HID + lane];
            float v1 = H[(size_t)s0.y * HID + lane];
            float v2 = H[(size_t)s0.z * HID + lane];
            float v3 = H[(size_t)s0.w * HID + lane];
            acc += p0.x * v0 + p0.y * v1 + p0.z * v2 + p0.w * v3;
        }
        for (; j < deg; ++j)
            acc += lp[wv][j] * H[(size_t)ls[wv][j] * HID + lane];
    } else {
        // general path (deg > 64): two-pass shuffle version
        float lmax = -1e30f;
        for (int pos = start + lane; pos < end; pos += 64) {
            int2 e = csr[pos];
            float al = Asrc[e.x] + ad + c * __int_as_float(e.y);
            al = (al > 0.f) ? al : NEG * al;
            lmax = fmaxf(lmax, al);
        }
        float m = wave_max(lmax);
        float lsum = 0.f;
        for (int base = start; base < end; base += 64) {
            int pos = base + lane;
            int src = 0; float p = 0.f;
            if (pos < end) {
                int2 e = csr[pos];
                src = e.x;
                float al = Asrc[src] + ad + c * __int_as_float(e.y);
                al = (al > 0.f) ? al : NEG * al;
                p = __expf(al - m);
                lsum += p;
            }
            int cnt = min(64, end - base);
            for (int j = 0; j < cnt; ++j) {
                float pj = __shfl(p, j, 64);
                int   sj = __shfl(src, j, 64);
                acc += pj * H[(size_t)sj * HID + lane];
            }
        }
        denom = wave_sum(lsum);
    }

    acc = acc / (denom + 1e-16f) + bias[lane];
    if (do_relu) acc = fmaxf(acc, 0.f);
    Out[(size_t)n * HID + lane] = acc;
}

// ---- mean pool (batch sorted): 16-node chunks, batched loads on single-group path ----
__global__ void pool_k(const float* __restrict__ act, const int* __restrict__ batch,
                       float* __restrict__ sums, float* __restrict__ cnt) {
    const int CHUNK = 16;
    int wv = threadIdx.x >> 6, lane = threadIdx.x & 63;
    int wid = blockIdx.x * 4 + wv;
    int base = wid * CHUNK;
    if (base >= N_NODES) return;
    int end = min(base + CHUNK, N_NODES);
    int g0 = batch[base], g1 = batch[end - 1];
    if (g0 == g1) {
        float acc = 0.f;
        int n = base;
        for (; n + 4 <= end; n += 4) {
            float v0 = act[(size_t)n * HID + lane];
            float v1 = act[(size_t)(n + 1) * HID + lane];
            float v2 = act[(size_t)(n + 2) * HID + lane];
            float v3 = act[(size_t)(n + 3) * HID + lane];
            acc += v0 + v1 + v2 + v3;
        }
        for (; n < end; ++n) acc += act[(size_t)n * HID + lane];
        atomicAdd(&sums[(size_t)g0 * HID + lane], acc);
        if (lane == 0) atomicAdd(&cnt[g0], (float)(end - base));
    } else {
        float acc = 0.f;
        int cur = g0, cl = 0;
        for (int n = base; n < end; ++n) {
            int g = batch[n];
            if (g != cur) {
                atomicAdd(&sums[(size_t)cur * HID + lane], acc);
                if (lane == 0) atomicAdd(&cnt[cur], (float)cl);
                acc = 0.f; cl = 0; cur = g;
            }
            acc += act[(size_t)n * HID + lane];
            cl++;
        }
        atomicAdd(&sums[(size_t)cur * HID + lane], acc);
        if (lane == 0) atomicAdd(&cnt[cur], (float)cl);
    }
}

// ---- readout: mean, linear, sigmoid ----
__global__ void readout_k(const float* __restrict__ sums, const float* __restrict__ cnt,
                          const float* __restrict__ lin_w, const float* __restrict__ lin_b,
                          float* __restrict__ out) {
    int wv = threadIdx.x >> 6, lane = threadIdx.x & 63;
    int g = blockIdx.x * 4 + wv;
    if (g >= NG) return;
    float c = fmaxf(cnt[g], 1.f);
    float v = sums[(size_t)g * HID + lane] / c * lin_w[lane];
    v = wave_sum(v);
    if (lane == 0) {
        float z = v + lin_b[0];
        out[g] = 1.f / (1.f + __expf(-z));
    }
}

extern "C" void kernel_launch(void* const* d_in, const int* in_sizes, int n_in,
                              void* d_out, int out_size, void* d_ws, size_t ws_size,
                              hipStream_t stream) {
    const float* x     = (const float*)d_in[0];
    const int*   ei    = (const int*)d_in[1];
    const float* ew    = (const float*)d_in[2];
    const int*   batch = (const int*)d_in[3];
    const float* W1  = (const float*)d_in[4];
    const float* as1 = (const float*)d_in[5];
    const float* ad1 = (const float*)d_in[6];
    const float* We1 = (const float*)d_in[7];
    const float* ae1 = (const float*)d_in[8];
    const float* b1  = (const float*)d_in[9];
    const float* W2  = (const float*)d_in[10];
    const float* as2 = (const float*)d_in[11];
    const float* ad2 = (const float*)d_in[12];
    const float* We2 = (const float*)d_in[13];
    const float* ae2 = (const float*)d_in[14];
    const float* b2  = (const float*)d_in[15];
    const float* W3  = (const float*)d_in[16];
    const float* as3 = (const float*)d_in[17];
    const float* ad3 = (const float*)d_in[18];
    const float* We3 = (const float*)d_in[19];
    const float* ae3 = (const float*)d_in[20];
    const float* b3  = (const float*)d_in[21];
    const float* lin_w = (const float*)d_in[22];
    const float* lin_b = (const float*)d_in[23];
    float* out = (float*)d_out;

    char* w = (char*)d_ws;
    size_t off = 0;
    auto alloc = [&](size_t bytes) -> void* {
        void* p = w + off;
        off = (off + bytes + 255) & ~(size_t)255;
        return p;
    };
    // zeroed region (memset each call; ws is poisoned)
    int*   counts   = (int*)alloc(N_NODES * sizeof(int));
    float* mean_acc = (float*)alloc(sizeof(float));
    float* cnt_g    = (float*)alloc(NG * sizeof(float));
    float* sums_g   = (float*)alloc((size_t)NG * HID * sizeof(float));
    size_t zero_bytes = off;
    // non-zeroed
    float* ce      = (float*)alloc(4 * sizeof(float));
    float* mean    = (float*)alloc(sizeof(float));
    int*   row_ptr = (int*)alloc((N_NODES + 1) * sizeof(int));
    int*   fill    = (int*)alloc(N_NODES * sizeof(int));
    int*   bsums   = (int*)alloc(64 * sizeof(int));
    int2*  csr     = (int2*)alloc((size_t)ET * sizeof(int2));
    float* a_src   = (float*)alloc(N_NODES * sizeof(float));
    float* a_dst   = (float*)alloc(N_NODES * sizeof(float));
    float* hbuf    = (float*)alloc((size_t)N_NODES * HID * sizeof(float));
    float* actA    = (float*)alloc((size_t)N_NODES * HID * sizeof(float));
    float* actB    = (float*)alloc((size_t)N_NODES * HID * sizeof(float));

    hipMemsetAsync(d_ws, 0, zero_bytes, stream);

    int egrid = (ET + 255) / 256;
    edge_prep_k<<<egrid, 256, 0, stream>>>(ei, ew, counts, mean_acc);
    int sgrid = (N_NODES + 1023) / 1024;  // 49
    scan1_k<<<sgrid, 1024, 0, stream>>>(counts, row_ptr, bsums);
    small_k<<<1, 256, 0, stream>>>(bsums, sgrid, mean_acc, mean,
                                   We1, ae1, We2, ae2, We3, ae3, ce);
    scan3_k<<<sgrid, 1024, 0, stream>>>(counts, row_ptr, bsums, fill);
    scatter_k<<<egrid, 256, 0, stream>>>(ei, ew, mean, fill, csr);

    int ggrid = (N_NODES + 63) / 64;
    int agrid = (N_NODES + 3) / 4;

    size_t lds1 = (size_t)(F_IN_DIM * HID + 64 * 17) * sizeof(float);
    size_t lds2 = (size_t)(HID * HID + 64 * 17) * sizeof(float);

    // layer 1
    gemm_att_k<<<ggrid, 256, lds1, stream>>>(x, F_IN_DIM, W1, as1, ad1, hbuf, a_src, a_dst);
    aggregate_k<<<agrid, 256, 0, stream>>>(hbuf, row_ptr, csr, a_src, a_dst, ce, 0, b1, actA, 1);
    // layer 2
    gemm_att_k<<<ggrid, 256, lds2, stream>>>(actA, HID, W2, as2, ad2, hbuf, a_src, a_dst);
    aggregate_k<<<agrid, 256, 0, stream>>>(hbuf, row_ptr, csr, a_src, a_dst, ce, 1, b2, actB, 1);
    // layer 3
    gemm_att_k<<<ggrid, 256, lds2, stream>>>(actB, HID, W3, as3, ad3, hbuf, a_src, a_dst);
    aggregate_k<<<agrid, 256, 0, stream>>>(hbuf, row_ptr, csr, a_src, a_dst, ce, 2, b3, actA, 0);

    // pool + readout
    int pgrid = ((N_NODES + 15) / 16 + 3) / 4;
    pool_k<<<pgrid, 256, 0, stream>>>(actA, batch, sums_g, cnt_g);
    readout_k<<<NG / 4, 256, 0, stream>>>(sums_g, cnt_g, lin_w, lin_b, out);
}

// Round 4
// 357.682 us; speedup vs baseline: 1.7220x; 1.1166x over previous
//
#include <hip/hip_runtime.h>
#include <math.h>

#define N_NODES 50000
#define N_EDGES 800000
#define ET (N_EDGES + N_NODES)   // 850000 incl. self-loops
#define F_IN_DIM 128
#define HID 64
#define NG 512
#define NEG 0.2f
#define SLICE ((N_NODES + 7) / 8)   // 6250 nodes per XCD slice
#define EPB 2048                     // edges per 8-block group

static __device__ __forceinline__ float wave_sum(float v) {
    for (int o = 32; o; o >>= 1) v += __shfl_xor(v, o, 64);
    return v;
}

// ---- fused: in-degree count (XCD-sliced) + mean(edge_weight) partial reduce ----
__global__ __launch_bounds__(256) void edge_prep_k(const int* __restrict__ ei,
                                                   const float* __restrict__ ew,
                                                   int* __restrict__ counts,
                                                   float* __restrict__ mean_acc) {
    int grp = blockIdx.x >> 3, slice = blockIdx.x & 7;
    int lo = slice * SLICE, hi = lo + SLICE;
    int base = grp * EPB;
    int lim = min(base + EPB, ET);
    float s = 0.f;
    for (int e = base + threadIdx.x; e < lim; e += 256) {
        int dst;
        if (e < N_EDGES) {
            dst = ei[N_EDGES + e];
            if (slice == 0) s += ew[e];
        } else dst = e - N_EDGES;
        if (dst >= lo && dst < hi) atomicAdd(&counts[dst], 1);
    }
    if (slice == 0) {
        s = wave_sum(s);
        __shared__ float tmp[4];
        int lane = threadIdx.x & 63, wv = threadIdx.x >> 6;
        if (lane == 0) tmp[wv] = s;
        __syncthreads();
        if (threadIdx.x == 0) atomicAdd(mean_acc, tmp[0] + tmp[1] + tmp[2] + tmp[3]);
    }
}

// ---- block-wise inclusive scan (1024/block) ----
__global__ void scan1_k(const int* __restrict__ counts, int* __restrict__ row_ptr,
                        int* __restrict__ bsums) {
    __shared__ int tmp[1024];
    int gid = blockIdx.x * 1024 + threadIdx.x;
    int v = (gid < N_NODES) ? counts[gid] : 0;
    tmp[threadIdx.x] = v;
    __syncthreads();
    for (int o = 1; o < 1024; o <<= 1) {
        int t = (threadIdx.x >= (unsigned)o) ? tmp[threadIdx.x - o] : 0;
        __syncthreads();
        tmp[threadIdx.x] += t;
        __syncthreads();
    }
    if (gid < N_NODES) row_ptr[gid + 1] = tmp[threadIdx.x];
    if (threadIdx.x == 1023) bsums[blockIdx.x] = tmp[1023];
}

// ---- fused: wave-scan of block sums + mean finalize + ce[l]=dot(We_l,ae_l) ----
__global__ void small_k(int* __restrict__ bsums, int nb,
                        const float* __restrict__ acc, float* __restrict__ mean_out,
                        const float* __restrict__ We1, const float* __restrict__ ae1,
                        const float* __restrict__ We2, const float* __restrict__ ae2,
                        const float* __restrict__ We3, const float* __restrict__ ae3,
                        float* __restrict__ ce) {
    int wv = threadIdx.x >> 6, lane = threadIdx.x & 63;
    if (wv == 0) {
        int orig = (lane < nb) ? bsums[lane] : 0;
        int v = orig;
        #pragma unroll
        for (int o = 1; o < 64; o <<= 1) {
            int t = __shfl_up(v, o, 64);
            if (lane >= o) v += t;
        }
        if (lane < nb) bsums[lane] = v - orig;   // exclusive
        if (lane == 63) mean_out[0] = acc[0] / (float)N_EDGES;
    } else {
        const float* We = (wv == 1) ? We1 : (wv == 2) ? We2 : We3;
        const float* ae = (wv == 1) ? ae1 : (wv == 2) ? ae2 : ae3;
        float v = We[lane] * ae[lane];
        v = wave_sum(v);
        if (lane == 0) ce[wv - 1] = v;
    }
}

__global__ void scan3_k(const int* __restrict__ counts, int* __restrict__ row_ptr,
                        const int* __restrict__ bsums, int* __restrict__ fill) {
    int gid = blockIdx.x * 1024 + threadIdx.x;
    if (gid >= N_NODES) return;
    int o = bsums[blockIdx.x];
    int inc = row_ptr[gid + 1] + o;
    row_ptr[gid + 1] = inc;
    fill[gid] = inc - counts[gid];
    if (gid == 0) row_ptr[0] = 0;
}

// ---- scatter edges into CSR order (XCD-sliced by dst) ----
__global__ __launch_bounds__(256) void scatter_k(const int* __restrict__ ei,
                                                 const float* __restrict__ ew,
                                                 const float* __restrict__ mean,
                                                 int* __restrict__ fill,
                                                 int2* __restrict__ csr) {
    int grp = blockIdx.x >> 3, slice = blockIdx.x & 7;
    int lo = slice * SLICE, hi = lo + SLICE;
    int base = grp * EPB;
    int lim = min(base + EPB, ET);
    float mv = mean[0];
    for (int e = base + threadIdx.x; e < lim; e += 256) {
        int src, dst; float w;
        if (e < N_EDGES) { src = ei[e]; dst = ei[N_EDGES + e]; w = ew[e]; }
        else             { src = dst = e - N_EDGES; w = mv; }
        if (dst >= lo && dst < hi) {
            int pos = atomicAdd(&fill[dst], 1);
            csr[pos] = make_int2(src, __float_as_int(w));
        }
    }
}

// ---- H = X @ W (register-tiled), fused a_src/a_dst ----
__global__ __launch_bounds__(256) void gemm_att_k(
        const float* __restrict__ X, int F,
        const float* __restrict__ W,
        const float* __restrict__ as_, const float* __restrict__ ad_,
        float* __restrict__ H, float* __restrict__ Asrc,
        float* __restrict__ Adst) {
    extern __shared__ float smem[];
    float* Ws = smem;               // F*64 floats
    float* Xs = smem + F * HID;     // 64*17 floats
    const int tid = threadIdx.x;
    const int tx = tid & 15, ty = tid >> 4;
    const int rowBase = blockIdx.x * 64;

    {
        const float4* W4 = (const float4*)W;
        float4* Ws4 = (float4*)Ws;
        int n4 = (F * HID) >> 2;
        for (int i = tid; i < n4; i += 256) Ws4[i] = W4[i];
    }

    float4 acc0 = {0,0,0,0}, acc1 = {0,0,0,0}, acc2 = {0,0,0,0}, acc3 = {0,0,0,0};

    const int xrow = tid >> 2;
    const int xkq  = tid & 3;
    const int nkt = F >> 4;

    for (int kt = 0; kt < nkt; ++kt) {
        __syncthreads();
        int k0 = kt << 4;
        int grow = rowBase + xrow;
        float4 xv = {0,0,0,0};
        if (grow < N_NODES)
            xv = *(const float4*)(X + (size_t)grow * F + k0 + (xkq << 2));
        float* xd = Xs + xrow * 17 + (xkq << 2);
        xd[0] = xv.x; xd[1] = xv.y; xd[2] = xv.z; xd[3] = xv.w;
        __syncthreads();

        #pragma unroll
        for (int kk = 0; kk < 16; ++kk) {
            float4 b = *(const float4*)&Ws[(k0 + kk) * HID + (tx << 2)];
            float a0 = Xs[(ty * 4 + 0) * 17 + kk];
            float a1 = Xs[(ty * 4 + 1) * 17 + kk];
            float a2 = Xs[(ty * 4 + 2) * 17 + kk];
            float a3 = Xs[(ty * 4 + 3) * 17 + kk];
            acc0.x += a0 * b.x; acc0.y += a0 * b.y; acc0.z += a0 * b.z; acc0.w += a0 * b.w;
            acc1.x += a1 * b.x; acc1.y += a1 * b.y; acc1.z += a1 * b.z; acc1.w += a1 * b.w;
            acc2.x += a2 * b.x; acc2.y += a2 * b.y; acc2.z += a2 * b.z; acc2.w += a2 * b.w;
            acc3.x += a3 * b.x; acc3.y += a3 * b.y; acc3.z += a3 * b.z; acc3.w += a3 * b.w;
        }
    }

    float4 as4 = *(const float4*)(as_ + (tx << 2));
    float4 ad4 = *(const float4*)(ad_ + (tx << 2));
    float4 accs[4] = {acc0, acc1, acc2, acc3};
    #pragma unroll
    for (int i = 0; i < 4; ++i) {
        int row = rowBase + ty * 4 + i;
        if (row >= N_NODES) break;
        float4 a = accs[i];
        *(float4*)(H + (size_t)row * HID + (tx << 2)) = a;
        float vs = a.x * as4.x + a.y * as4.y + a.z * as4.z + a.w * as4.w;
        float vd = a.x * ad4.x + a.y * ad4.y + a.z * ad4.z + a.w * ad4.w;
        #pragma unroll
        for (int o = 8; o; o >>= 1) { vs += __shfl_xor(vs, o, 64); vd += __shfl_xor(vd, o, 64); }
        if (tx == 0) { Asrc[row] = vs; Adst[row] = vd; }
    }
}

// ---- per-dst-node softmax + weighted gather ----
// 16 lanes per node (float4 per lane), 4 nodes per wave, 16 nodes per block.
// Per gather batch: 8 independent float4 H-row loads per lane-group -> 32/wave.
__global__ __launch_bounds__(256) void aggregate_k(
        const float* __restrict__ H, const int* __restrict__ row_ptr,
        const int2* __restrict__ csr,
        const float* __restrict__ Asrc, const float* __restrict__ Adst,
        const float* __restrict__ ceArr, int ci,
        const float* __restrict__ bias, float* __restrict__ Out,
        int do_relu) {
    __shared__ float lp[16][64];
    __shared__ int   ls[16][64];
    int wv = threadIdx.x >> 6, lane = threadIdx.x & 63;
    int qid = lane >> 4, qlane = lane & 15;
    int slot = wv * 4 + qid;
    int n = blockIdx.x * 16 + wv * 4 + qid;
    if (n >= N_NODES) return;
    int start = row_ptr[n], end = row_ptr[n + 1];
    int deg = end - start;
    float c = ceArr[ci];
    float ad = Adst[n];
    float4 acc = {0, 0, 0, 0};
    float denom;

    if (deg <= 64) {
        // alpha for up to 4 edges per lane
        float alv[4]; int srcv[4];
        #pragma unroll
        for (int t = 0; t < 4; ++t) {
            int j = qlane + (t << 4);
            alv[t] = -1e30f; srcv[t] = 0;
            if (j < deg) {
                int2 e = csr[start + j];
                srcv[t] = e.x;
                float a = Asrc[e.x] + ad + c * __int_as_float(e.y);
                alv[t] = (a > 0.f) ? a : NEG * a;
            }
        }
        float lm = fmaxf(fmaxf(alv[0], alv[1]), fmaxf(alv[2], alv[3]));
        #pragma unroll
        for (int o = 1; o < 16; o <<= 1) lm = fmaxf(lm, __shfl_xor(lm, o, 64));
        float lsum = 0.f;
        #pragma unroll
        for (int t = 0; t < 4; ++t) {
            int j = qlane + (t << 4);
            float p = 0.f;
            if (j < deg) { p = __expf(alv[t] - lm); lsum += p; }
            lp[slot][j] = p;
            ls[slot][j] = srcv[t];
        }
        #pragma unroll
        for (int o = 1; o < 16; o <<= 1) lsum += __shfl_xor(lsum, o, 64);
        denom = lsum;
        __builtin_amdgcn_wave_barrier();
        int dpad = (deg + 7) & ~7;
        for (int j = 0; j < dpad; j += 8) {
            float4 p0 = *(float4*)&lp[slot][j];
            float4 p1 = *(float4*)&lp[slot][j + 4];
            int4 s0 = *(int4*)&ls[slot][j];
            int4 s1 = *(int4*)&ls[slot][j + 4];
            float4 h0 = *(const float4*)(H + (size_t)s0.x * HID + (qlane << 2));
            float4 h1 = *(const float4*)(H + (size_t)s0.y * HID + (qlane << 2));
            float4 h2 = *(const float4*)(H + (size_t)s0.z * HID + (qlane << 2));
            float4 h3 = *(const float4*)(H + (size_t)s0.w * HID + (qlane << 2));
            float4 h4 = *(const float4*)(H + (size_t)s1.x * HID + (qlane << 2));
            float4 h5 = *(const float4*)(H + (size_t)s1.y * HID + (qlane << 2));
            float4 h6 = *(const float4*)(H + (size_t)s1.z * HID + (qlane << 2));
            float4 h7 = *(const float4*)(H + (size_t)s1.w * HID + (qlane << 2));
            acc.x += p0.x*h0.x + p0.y*h1.x + p0.z*h2.x + p0.w*h3.x
                   + p1.x*h4.x + p1.y*h5.x + p1.z*h6.x + p1.w*h7.x;
            acc.y += p0.x*h0.y + p0.y*h1.y + p0.z*h2.y + p0.w*h3.y
                   + p1.x*h4.y + p1.y*h5.y + p1.z*h6.y + p1.w*h7.y;
            acc.z += p0.x*h0.z + p0.y*h1.z + p0.z*h2.z + p0.w*h3.z
                   + p1.x*h4.z + p1.y*h5.z + p1.z*h6.z + p1.w*h7.z;
            acc.w += p0.x*h0.w + p0.y*h1.w + p0.z*h2.w + p0.w*h3.w
                   + p1.x*h4.w + p1.y*h5.w + p1.z*h6.w + p1.w*h7.w;
        }
    } else {
        // general path (deg > 64), per 16-lane group
        float lm = -1e30f;
        for (int pos = start + qlane; pos < end; pos += 16) {
            int2 e = csr[pos];
            float a = Asrc[e.x] + ad + c * __int_as_float(e.y);
            a = (a > 0.f) ? a : NEG * a;
            lm = fmaxf(lm, a);
        }
        #pragma unroll
        for (int o = 1; o < 16; o <<= 1) lm = fmaxf(lm, __shfl_xor(lm, o, 64));
        float lsum = 0.f;
        for (int base = start; base < end; base += 64) {
            int cnt = min(64, end - base);
            #pragma unroll
            for (int t = 0; t < 4; ++t) {
                int j = qlane + (t << 4);
                float p = 0.f; int s = 0;
                if (j < cnt) {
                    int2 e = csr[base + j];
                    s = e.x;
                    float a = Asrc[s] + ad + c * __int_as_float(e.y);
                    a = (a > 0.f) ? a : NEG * a;
                    p = __expf(a - lm);
                    lsum += p;
                }
                lp[slot][j] = p;
                ls[slot][j] = s;
            }
            __builtin_amdgcn_wave_barrier();
            int cpad = (cnt + 7) & ~7;
            for (int j = 0; j < cpad; j += 8) {
                float4 p0 = *(float4*)&lp[slot][j];
                float4 p1 = *(float4*)&lp[slot][j + 4];
                int4 s0 = *(int4*)&ls[slot][j];
                int4 s1 = *(int4*)&ls[slot][j + 4];
                float4 h0 = *(const float4*)(H + (size_t)s0.x * HID + (qlane << 2));
                float4 h1 = *(const float4*)(H + (size_t)s0.y * HID + (qlane << 2));
                float4 h2 = *(const float4*)(H + (size_t)s0.z * HID + (qlane << 2));
                float4 h3 = *(const float4*)(H + (size_t)s0.w * HID + (qlane << 2));
                float4 h4 = *(const float4*)(H + (size_t)s1.x * HID + (qlane << 2));
                float4 h5 = *(const float4*)(H + (size_t)s1.y * HID + (qlane << 2));
                float4 h6 = *(const float4*)(H + (size_t)s1.z * HID + (qlane << 2));
                float4 h7 = *(const float4*)(H + (size_t)s1.w * HID + (qlane << 2));
                acc.x += p0.x*h0.x + p0.y*h1.x + p0.z*h2.x + p0.w*h3.x
                       + p1.x*h4.x + p1.y*h5.x + p1.z*h6.x + p1.w*h7.x;
                acc.y += p0.x*h0.y + p0.y*h1.y + p0.z*h2.y + p0.w*h3.y
                       + p1.x*h4.y + p1.y*h5.y + p1.z*h6.y + p1.w*h7.y;
                acc.z += p0.x*h0.z + p0.y*h1.z + p0.z*h2.z + p0.w*h3.z
                       + p1.x*h4.z + p1.y*h5.z + p1.z*h6.z + p1.w*h7.z;
                acc.w += p0.x*h0.w + p0.y*h1.w + p0.z*h2.w + p0.w*h3.w
                       + p1.x*h4.w + p1.y*h5.w + p1.z*h6.w + p1.w*h7.w;
            }
            __builtin_amdgcn_wave_barrier();
        }
        #pragma unroll
        for (int o = 1; o < 16; o <<= 1) lsum += __shfl_xor(lsum, o, 64);
        denom = lsum;
    }

    float inv = 1.f / (denom + 1e-16f);
    float4 b4 = *(const float4*)(bias + (qlane << 2));
    acc.x = acc.x * inv + b4.x;
    acc.y = acc.y * inv + b4.y;
    acc.z = acc.z * inv + b4.z;
    acc.w = acc.w * inv + b4.w;
    if (do_relu) {
        acc.x = fmaxf(acc.x, 0.f); acc.y = fmaxf(acc.y, 0.f);
        acc.z = fmaxf(acc.z, 0.f); acc.w = fmaxf(acc.w, 0.f);
    }
    *(float4*)(Out + (size_t)n * HID + (qlane << 2)) = acc;
}

// ---- mean pool (batch sorted): 16-node chunks, batched loads on single-group path ----
__global__ void pool_k(const float* __restrict__ act, const int* __restrict__ batch,
                       float* __restrict__ sums, float* __restrict__ cnt) {
    const int CHUNK = 16;
    int wv = threadIdx.x >> 6, lane = threadIdx.x & 63;
    int wid = blockIdx.x * 4 + wv;
    int base = wid * CHUNK;
    if (base >= N_NODES) return;
    int end = min(base + CHUNK, N_NODES);
    int g0 = batch[base], g1 = batch[end - 1];
    if (g0 == g1) {
        float acc = 0.f;
        int n = base;
        for (; n + 4 <= end; n += 4) {
            float v0 = act[(size_t)n * HID + lane];
            float v1 = act[(size_t)(n + 1) * HID + lane];
            float v2 = act[(size_t)(n + 2) * HID + lane];
            float v3 = act[(size_t)(n + 3) * HID + lane];
            acc += v0 + v1 + v2 + v3;
        }
        for (; n < end; ++n) acc += act[(size_t)n * HID + lane];
        atomicAdd(&sums[(size_t)g0 * HID + lane], acc);
        if (lane == 0) atomicAdd(&cnt[g0], (float)(end - base));
    } else {
        float acc = 0.f;
        int cur = g0, cl = 0;
        for (int n = base; n < end; ++n) {
            int g = batch[n];
            if (g != cur) {
                atomicAdd(&sums[(size_t)cur * HID + lane], acc);
                if (lane == 0) atomicAdd(&cnt[cur], (float)cl);
                acc = 0.f; cl = 0; cur = g;
            }
            acc += act[(size_t)n * HID + lane];
            cl++;
        }
        atomicAdd(&sums[(size_t)cur * HID + lane], acc);
        if (lane == 0) atomicAdd(&cnt[cur], (float)cl);
    }
}

// ---- readout: mean, linear, sigmoid ----
__global__ void readout_k(const float* __restrict__ sums, const float* __restrict__ cnt,
                          const float* __restrict__ lin_w, const float* __restrict__ lin_b,
                          float* __restrict__ out) {
    int wv = threadIdx.x >> 6, lane = threadIdx.x & 63;
    int g = blockIdx.x * 4 + wv;
    if (g >= NG) return;
    float c = fmaxf(cnt[g], 1.f);
    float v = sums[(size_t)g * HID + lane] / c * lin_w[lane];
    v = wave_sum(v);
    if (lane == 0) {
        float z = v + lin_b[0];
        out[g] = 1.f / (1.f + __expf(-z));
    }
}

extern "C" void kernel_launch(void* const* d_in, const int* in_sizes, int n_in,
                              void* d_out, int out_size, void* d_ws, size_t ws_size,
                              hipStream_t stream) {
    const float* x     = (const float*)d_in[0];
    const int*   ei    = (const int*)d_in[1];
    const float* ew    = (const float*)d_in[2];
    const int*   batch = (const int*)d_in[3];
    const float* W1  = (const float*)d_in[4];
    const float* as1 = (const float*)d_in[5];
    const float* ad1 = (const float*)d_in[6];
    const float* We1 = (const float*)d_in[7];
    const float* ae1 = (const float*)d_in[8];
    const float* b1  = (const float*)d_in[9];
    const float* W2  = (const float*)d_in[10];
    const float* as2 = (const float*)d_in[11];
    const float* ad2 = (const float*)d_in[12];
    const float* We2 = (const float*)d_in[13];
    const float* ae2 = (const float*)d_in[14];
    const float* b2  = (const float*)d_in[15];
    const float* W3  = (const float*)d_in[16];
    const float* as3 = (const float*)d_in[17];
    const float* ad3 = (const float*)d_in[18];
    const float* We3 = (const float*)d_in[19];
    const float* ae3 = (const float*)d_in[20];
    const float* b3  = (const float*)d_in[21];
    const float* lin_w = (const float*)d_in[22];
    const float* lin_b = (const float*)d_in[23];
    float* out = (float*)d_out;

    char* w = (char*)d_ws;
    size_t off = 0;
    auto alloc = [&](size_t bytes) -> void* {
        void* p = w + off;
        off = (off + bytes + 255) & ~(size_t)255;
        return p;
    };
    // zeroed region (memset each call; ws is poisoned)
    int*   counts   = (int*)alloc(N_NODES * sizeof(int));
    float* mean_acc = (float*)alloc(sizeof(float));
    float* cnt_g    = (float*)alloc(NG * sizeof(float));
    float* sums_g   = (float*)alloc((size_t)NG * HID * sizeof(float));
    size_t zero_bytes = off;
    // non-zeroed
    float* ce      = (float*)alloc(4 * sizeof(float));
    float* mean    = (float*)alloc(sizeof(float));
    int*   row_ptr = (int*)alloc((N_NODES + 1) * sizeof(int));
    int*   fill    = (int*)alloc(N_NODES * sizeof(int));
    int*   bsums   = (int*)alloc(64 * sizeof(int));
    int2*  csr     = (int2*)alloc((size_t)ET * sizeof(int2));
    float* a_src   = (float*)alloc(N_NODES * sizeof(float));
    float* a_dst   = (float*)alloc(N_NODES * sizeof(float));
    float* hbuf    = (float*)alloc((size_t)N_NODES * HID * sizeof(float));
    float* actA    = (float*)alloc((size_t)N_NODES * HID * sizeof(float));
    float* actB    = (float*)alloc((size_t)N_NODES * HID * sizeof(float));

    hipMemsetAsync(d_ws, 0, zero_bytes, stream);

    int xgrid = ((ET + EPB - 1) / EPB) * 8;   // 416 * 8
    edge_prep_k<<<xgrid, 256, 0, stream>>>(ei, ew, counts, mean_acc);
    int sgrid = (N_NODES + 1023) / 1024;  // 49
    scan1_k<<<sgrid, 1024, 0, stream>>>(counts, row_ptr, bsums);
    small_k<<<1, 256, 0, stream>>>(bsums, sgrid, mean_acc, mean,
                                   We1, ae1, We2, ae2, We3, ae3, ce);
    scan3_k<<<sgrid, 1024, 0, stream>>>(counts, row_ptr, bsums, fill);
    scatter_k<<<xgrid, 256, 0, stream>>>(ei, ew, mean, fill, csr);

    int ggrid = (N_NODES + 63) / 64;
    int agrid = (N_NODES + 15) / 16;

    size_t lds1 = (size_t)(F_IN_DIM * HID + 64 * 17) * sizeof(float);
    size_t lds2 = (size_t)(HID * HID + 64 * 17) * sizeof(float);

    // layer 1
    gemm_att_k<<<ggrid, 256, lds1, stream>>>(x, F_IN_DIM, W1, as1, ad1, hbuf, a_src, a_dst);
    aggregate_k<<<agrid, 256, 0, stream>>>(hbuf, row_ptr, csr, a_src, a_dst, ce, 0, b1, actA, 1);
    // layer 2
    gemm_att_k<<<ggrid, 256, lds2, stream>>>(actA, HID, W2, as2, ad2, hbuf, a_src, a_dst);
    aggregate_k<<<agrid, 256, 0, stream>>>(hbuf, row_ptr, csr, a_src, a_dst, ce, 1, b2, actB, 1);
    // layer 3
    gemm_att_k<<<ggrid, 256, lds2, stream>>>(actB, HID, W3, as3, ad3, hbuf, a_src, a_dst);
    aggregate_k<<<agrid, 256, 0, stream>>>(hbuf, row_ptr, csr, a_src, a_dst, ce, 2, b3, actA, 0);

    // pool + readout
    int pgrid = ((N_NODES + 15) / 16 + 3) / 4;
    pool_k<<<pgrid, 256, 0, stream>>>(actA, batch, sums_g, cnt_g);
    readout_k<<<NG / 4, 256, 0, stream>>>(sums_g, cnt_g, lin_w, lin_b, out);
}

// Round 5
// 325.622 us; speedup vs baseline: 1.8916x; 1.0985x over previous
//
#include <hip/hip_runtime.h>
#include <math.h>

#define N_NODES 50000
#define N_EDGES 800000
#define ET (N_EDGES + N_NODES)   // 850000 incl. self-loops
#define F_IN_DIM 128
#define HID 64
#define NG 512
#define NEG 0.2f
#define SLICE ((N_NODES + 7) / 8)   // 6250 nodes per XCD slice
#define EPB 2048                     // edges per 8-block group

static __device__ __forceinline__ float wave_sum(float v) {
    for (int o = 32; o; o >>= 1) v += __shfl_xor(v, o, 64);
    return v;
}

// bf16 pack/unpack (RNE), no NaN inputs expected
static __device__ __forceinline__ unsigned short f2bf(float f) {
    union { float f; unsigned u; } v; v.f = f;
    unsigned r = (v.u + 0x7FFF + ((v.u >> 16) & 1)) >> 16;
    return (unsigned short)r;
}
static __device__ __forceinline__ float bf2f(unsigned short b) {
    union { unsigned u; float f; } v; v.u = ((unsigned)b) << 16;
    return v.f;
}

// ---- fused: in-degree count (XCD-sliced) + mean partial reduce + ce dots ----
__global__ __launch_bounds__(256) void edge_prep_k(
        const int* __restrict__ ei, const float* __restrict__ ew,
        int* __restrict__ counts, float* __restrict__ mean_acc,
        const float* __restrict__ We1, const float* __restrict__ ae1,
        const float* __restrict__ We2, const float* __restrict__ ae2,
        const float* __restrict__ We3, const float* __restrict__ ae3,
        float* __restrict__ ce) {
    int grp = blockIdx.x >> 3, slice = blockIdx.x & 7;
    int lo = slice * SLICE, hi = lo + SLICE;
    int base = grp * EPB;
    int lim = min(base + EPB, ET);
    float s = 0.f;
    for (int e = base + threadIdx.x; e < lim; e += 256) {
        int dst;
        if (e < N_EDGES) {
            dst = ei[N_EDGES + e];
            if (slice == 0) s += ew[e];
        } else dst = e - N_EDGES;
        if (dst >= lo && dst < hi) atomicAdd(&counts[dst], 1);
    }
    int lane = threadIdx.x & 63, wv = threadIdx.x >> 6;
    if (slice == 0) {
        s = wave_sum(s);
        __shared__ float tmp[4];
        if (lane == 0) tmp[wv] = s;
        __syncthreads();
        if (threadIdx.x == 0) atomicAdd(mean_acc, tmp[0] + tmp[1] + tmp[2] + tmp[3]);
    }
    if (blockIdx.x == 0 && wv >= 1) {
        const float* We = (wv == 1) ? We1 : (wv == 2) ? We2 : We3;
        const float* ae = (wv == 1) ? ae1 : (wv == 2) ? ae2 : ae3;
        float v = We[lane] * ae[lane];
        v = wave_sum(v);
        if (lane == 0) ce[wv - 1] = v;
    }
}

// ---- block-wise inclusive scan (1024/block) ----
__global__ void scan1_k(const int* __restrict__ counts, int* __restrict__ row_ptr,
                        int* __restrict__ bsums) {
    __shared__ int tmp[1024];
    int gid = blockIdx.x * 1024 + threadIdx.x;
    int v = (gid < N_NODES) ? counts[gid] : 0;
    tmp[threadIdx.x] = v;
    __syncthreads();
    for (int o = 1; o < 1024; o <<= 1) {
        int t = (threadIdx.x >= (unsigned)o) ? tmp[threadIdx.x - o] : 0;
        __syncthreads();
        tmp[threadIdx.x] += t;
        __syncthreads();
    }
    if (gid < N_NODES) row_ptr[gid + 1] = tmp[threadIdx.x];
    if (threadIdx.x == 1023) bsums[blockIdx.x] = tmp[1023];
}

// ---- finalize row_ptr + fill; self-scans bsums (wave 0, redundant per block) ----
__global__ void scan3_k(const int* __restrict__ counts, int* __restrict__ row_ptr,
                        const int* __restrict__ bsums, int* __restrict__ fill, int nb) {
    __shared__ int boff;
    int tid = threadIdx.x;
    if (tid < 64) {
        int orig = (tid < nb) ? bsums[tid] : 0;
        int v = orig;
        #pragma unroll
        for (int o = 1; o < 64; o <<= 1) {
            int t = __shfl_up(v, o, 64);
            if (tid >= o) v += t;
        }
        if (tid == (int)blockIdx.x) boff = v - orig;   // exclusive prefix for this block
    }
    __syncthreads();
    int gid = blockIdx.x * 1024 + tid;
    if (gid >= N_NODES) return;
    int o = boff;
    int inc = row_ptr[gid + 1] + o;
    row_ptr[gid + 1] = inc;
    fill[gid] = inc - counts[gid];
    if (gid == 0) row_ptr[0] = 0;
}

// ---- scatter edges into CSR order (XCD-sliced by dst), 4B packed entries ----
__global__ __launch_bounds__(256) void scatter_k(const int* __restrict__ ei,
                                                 const float* __restrict__ ew,
                                                 const float* __restrict__ mean_acc,
                                                 int* __restrict__ fill,
                                                 unsigned* __restrict__ csr) {
    int grp = blockIdx.x >> 3, slice = blockIdx.x & 7;
    int lo = slice * SLICE, hi = lo + SLICE;
    int base = grp * EPB;
    int lim = min(base + EPB, ET);
    float mv = mean_acc[0] * (1.0f / (float)N_EDGES);
    for (int e = base + threadIdx.x; e < lim; e += 256) {
        int src, dst; float w;
        if (e < N_EDGES) { src = ei[e]; dst = ei[N_EDGES + e]; w = ew[e]; }
        else             { src = dst = e - N_EDGES; w = mv; }
        if (dst >= lo && dst < hi) {
            int pos = atomicAdd(&fill[dst], 1);
            csr[pos] = (unsigned)(src & 0xFFFF) | ((unsigned)f2bf(w) << 16);
        }
    }
}

// ---- H = X @ W (register-tiled), H stored bf16, fused a_src/a_dst ----
__global__ __launch_bounds__(256) void gemm_att_k(
        const float* __restrict__ X, int F,
        const float* __restrict__ W,
        const float* __restrict__ as_, const float* __restrict__ ad_,
        unsigned short* __restrict__ H, float* __restrict__ Asrc,
        float* __restrict__ Adst) {
    extern __shared__ float smem[];
    float* Ws = smem;               // F*64 floats
    float* Xs = smem + F * HID;     // 64*17 floats
    const int tid = threadIdx.x;
    const int tx = tid & 15, ty = tid >> 4;
    const int rowBase = blockIdx.x * 64;

    {
        const float4* W4 = (const float4*)W;
        float4* Ws4 = (float4*)Ws;
        int n4 = (F * HID) >> 2;
        for (int i = tid; i < n4; i += 256) Ws4[i] = W4[i];
    }

    float4 acc0 = {0,0,0,0}, acc1 = {0,0,0,0}, acc2 = {0,0,0,0}, acc3 = {0,0,0,0};

    const int xrow = tid >> 2;
    const int xkq  = tid & 3;
    const int nkt = F >> 4;

    for (int kt = 0; kt < nkt; ++kt) {
        __syncthreads();
        int k0 = kt << 4;
        int grow = rowBase + xrow;
        float4 xv = {0,0,0,0};
        if (grow < N_NODES)
            xv = *(const float4*)(X + (size_t)grow * F + k0 + (xkq << 2));
        float* xd = Xs + xrow * 17 + (xkq << 2);
        xd[0] = xv.x; xd[1] = xv.y; xd[2] = xv.z; xd[3] = xv.w;
        __syncthreads();

        #pragma unroll
        for (int kk = 0; kk < 16; ++kk) {
            float4 b = *(const float4*)&Ws[(k0 + kk) * HID + (tx << 2)];
            float a0 = Xs[(ty * 4 + 0) * 17 + kk];
            float a1 = Xs[(ty * 4 + 1) * 17 + kk];
            float a2 = Xs[(ty * 4 + 2) * 17 + kk];
            float a3 = Xs[(ty * 4 + 3) * 17 + kk];
            acc0.x += a0 * b.x; acc0.y += a0 * b.y; acc0.z += a0 * b.z; acc0.w += a0 * b.w;
            acc1.x += a1 * b.x; acc1.y += a1 * b.y; acc1.z += a1 * b.z; acc1.w += a1 * b.w;
            acc2.x += a2 * b.x; acc2.y += a2 * b.y; acc2.z += a2 * b.z; acc2.w += a2 * b.w;
            acc3.x += a3 * b.x; acc3.y += a3 * b.y; acc3.z += a3 * b.z; acc3.w += a3 * b.w;
        }
    }

    float4 as4 = *(const float4*)(as_ + (tx << 2));
    float4 ad4 = *(const float4*)(ad_ + (tx << 2));
    float4 accs[4] = {acc0, acc1, acc2, acc3};
    #pragma unroll
    for (int i = 0; i < 4; ++i) {
        int row = rowBase + ty * 4 + i;
        if (row >= N_NODES) break;
        float4 a = accs[i];
        ushort4 hv;
        hv.x = f2bf(a.x); hv.y = f2bf(a.y); hv.z = f2bf(a.z); hv.w = f2bf(a.w);
        *(ushort4*)(H + (size_t)row * HID + (tx << 2)) = hv;
        float vs = a.x * as4.x + a.y * as4.y + a.z * as4.z + a.w * as4.w;
        float vd = a.x * ad4.x + a.y * ad4.y + a.z * ad4.z + a.w * ad4.w;
        #pragma unroll
        for (int o = 8; o; o >>= 1) { vs += __shfl_xor(vs, o, 64); vd += __shfl_xor(vd, o, 64); }
        if (tx == 0) { Asrc[row] = vs; Adst[row] = vd; }
    }
}

// ---- per-dst-node softmax + weighted gather ----
// 16 lanes per node, 4 nodes/wave; H gathered as bf16 ushort4 (8B/lane).
__global__ __launch_bounds__(256) void aggregate_k(
        const unsigned short* __restrict__ H, const int* __restrict__ row_ptr,
        const unsigned* __restrict__ csr,
        const float* __restrict__ Asrc, const float* __restrict__ Adst,
        const float* __restrict__ ceArr, int ci,
        const float* __restrict__ bias, float* __restrict__ Out,
        int do_relu) {
    __shared__ float lp[16][64];
    __shared__ int   ls[16][64];
    int wv = threadIdx.x >> 6, lane = threadIdx.x & 63;
    int qid = lane >> 4, qlane = lane & 15;
    int slot = wv * 4 + qid;
    int n = blockIdx.x * 16 + wv * 4 + qid;
    if (n >= N_NODES) return;
    int start = row_ptr[n], end = row_ptr[n + 1];
    int deg = end - start;
    float c = ceArr[ci];
    float ad = Adst[n];
    float4 acc = {0, 0, 0, 0};
    float denom;

    if (deg <= 64) {
        float alv[4]; int srcv[4];
        #pragma unroll
        for (int t = 0; t < 4; ++t) {
            int j = qlane + (t << 4);
            alv[t] = -1e30f; srcv[t] = 0;
            if (j < deg) {
                unsigned e = csr[start + j];
                int s = e & 0xFFFF;
                srcv[t] = s;
                float a = Asrc[s] + ad + c * bf2f((unsigned short)(e >> 16));
                alv[t] = (a > 0.f) ? a : NEG * a;
            }
        }
        float lm = fmaxf(fmaxf(alv[0], alv[1]), fmaxf(alv[2], alv[3]));
        #pragma unroll
        for (int o = 1; o < 16; o <<= 1) lm = fmaxf(lm, __shfl_xor(lm, o, 64));
        float lsum = 0.f;
        #pragma unroll
        for (int t = 0; t < 4; ++t) {
            int j = qlane + (t << 4);
            float p = 0.f;
            if (j < deg) { p = __expf(alv[t] - lm); lsum += p; }
            lp[slot][j] = p;
            ls[slot][j] = srcv[t];
        }
        #pragma unroll
        for (int o = 1; o < 16; o <<= 1) lsum += __shfl_xor(lsum, o, 64);
        denom = lsum;
        __builtin_amdgcn_wave_barrier();
        int dpad = (deg + 7) & ~7;
        for (int j = 0; j < dpad; j += 8) {
            float4 p0 = *(float4*)&lp[slot][j];
            float4 p1 = *(float4*)&lp[slot][j + 4];
            int4 s0 = *(int4*)&ls[slot][j];
            int4 s1 = *(int4*)&ls[slot][j + 4];
            ushort4 r0 = *(const ushort4*)(H + (size_t)s0.x * HID + (qlane << 2));
            ushort4 r1 = *(const ushort4*)(H + (size_t)s0.y * HID + (qlane << 2));
            ushort4 r2 = *(const ushort4*)(H + (size_t)s0.z * HID + (qlane << 2));
            ushort4 r3 = *(const ushort4*)(H + (size_t)s0.w * HID + (qlane << 2));
            ushort4 r4 = *(const ushort4*)(H + (size_t)s1.x * HID + (qlane << 2));
            ushort4 r5 = *(const ushort4*)(H + (size_t)s1.y * HID + (qlane << 2));
            ushort4 r6 = *(const ushort4*)(H + (size_t)s1.z * HID + (qlane << 2));
            ushort4 r7 = *(const ushort4*)(H + (size_t)s1.w * HID + (qlane << 2));
            acc.x += p0.x*bf2f(r0.x) + p0.y*bf2f(r1.x) + p0.z*bf2f(r2.x) + p0.w*bf2f(r3.x)
                   + p1.x*bf2f(r4.x) + p1.y*bf2f(r5.x) + p1.z*bf2f(r6.x) + p1.w*bf2f(r7.x);
            acc.y += p0.x*bf2f(r0.y) + p0.y*bf2f(r1.y) + p0.z*bf2f(r2.y) + p0.w*bf2f(r3.y)
                   + p1.x*bf2f(r4.y) + p1.y*bf2f(r5.y) + p1.z*bf2f(r6.y) + p1.w*bf2f(r7.y);
            acc.z += p0.x*bf2f(r0.z) + p0.y*bf2f(r1.z) + p0.z*bf2f(r2.z) + p0.w*bf2f(r3.z)
                   + p1.x*bf2f(r4.z) + p1.y*bf2f(r5.z) + p1.z*bf2f(r6.z) + p1.w*bf2f(r7.z);
            acc.w += p0.x*bf2f(r0.w) + p0.y*bf2f(r1.w) + p0.z*bf2f(r2.w) + p0.w*bf2f(r3.w)
                   + p1.x*bf2f(r4.w) + p1.y*bf2f(r5.w) + p1.z*bf2f(r6.w) + p1.w*bf2f(r7.w);
        }
    } else {
        float lm = -1e30f;
        for (int pos = start + qlane; pos < end; pos += 16) {
            unsigned e = csr[pos];
            float a = Asrc[e & 0xFFFF] + ad + c * bf2f((unsigned short)(e >> 16));
            a = (a > 0.f) ? a : NEG * a;
            lm = fmaxf(lm, a);
        }
        #pragma unroll
        for (int o = 1; o < 16; o <<= 1) lm = fmaxf(lm, __shfl_xor(lm, o, 64));
        float lsum = 0.f;
        for (int base = start; base < end; base += 64) {
            int cnt = min(64, end - base);
            #pragma unroll
            for (int t = 0; t < 4; ++t) {
                int j = qlane + (t << 4);
                float p = 0.f; int s = 0;
                if (j < cnt) {
                    unsigned e = csr[base + j];
                    s = e & 0xFFFF;
                    float a = Asrc[s] + ad + c * bf2f((unsigned short)(e >> 16));
                    a = (a > 0.f) ? a : NEG * a;
                    p = __expf(a - lm);
                    lsum += p;
                }
                lp[slot][j] = p;
                ls[slot][j] = s;
            }
            __builtin_amdgcn_wave_barrier();
            int cpad = (cnt + 7) & ~7;
            for (int j = 0; j < cpad; j += 8) {
                float4 p0 = *(float4*)&lp[slot][j];
                float4 p1 = *(float4*)&lp[slot][j + 4];
                int4 s0 = *(int4*)&ls[slot][j];
                int4 s1 = *(int4*)&ls[slot][j + 4];
                ushort4 r0 = *(const ushort4*)(H + (size_t)s0.x * HID + (qlane << 2));
                ushort4 r1 = *(const ushort4*)(H + (size_t)s0.y * HID + (qlane << 2));
                ushort4 r2 = *(const ushort4*)(H + (size_t)s0.z * HID + (qlane << 2));
                ushort4 r3 = *(const ushort4*)(H + (size_t)s0.w * HID + (qlane << 2));
                ushort4 r4 = *(const ushort4*)(H + (size_t)s1.x * HID + (qlane << 2));
                ushort4 r5 = *(const ushort4*)(H + (size_t)s1.y * HID + (qlane << 2));
                ushort4 r6 = *(const ushort4*)(H + (size_t)s1.z * HID + (qlane << 2));
                ushort4 r7 = *(const ushort4*)(H + (size_t)s1.w * HID + (qlane << 2));
                acc.x += p0.x*bf2f(r0.x) + p0.y*bf2f(r1.x) + p0.z*bf2f(r2.x) + p0.w*bf2f(r3.x)
                       + p1.x*bf2f(r4.x) + p1.y*bf2f(r5.x) + p1.z*bf2f(r6.x) + p1.w*bf2f(r7.x);
                acc.y += p0.x*bf2f(r0.y) + p0.y*bf2f(r1.y) + p0.z*bf2f(r2.y) + p0.w*bf2f(r3.y)
                       + p1.x*bf2f(r4.y) + p1.y*bf2f(r5.y) + p1.z*bf2f(r6.y) + p1.w*bf2f(r7.y);
                acc.z += p0.x*bf2f(r0.z) + p0.y*bf2f(r1.z) + p0.z*bf2f(r2.z) + p0.w*bf2f(r3.z)
                       + p1.x*bf2f(r4.z) + p1.y*bf2f(r5.z) + p1.z*bf2f(r6.z) + p1.w*bf2f(r7.z);
                acc.w += p0.x*bf2f(r0.w) + p0.y*bf2f(r1.w) + p0.z*bf2f(r2.w) + p0.w*bf2f(r3.w)
                       + p1.x*bf2f(r4.w) + p1.y*bf2f(r5.w) + p1.z*bf2f(r6.w) + p1.w*bf2f(r7.w);
            }
            __builtin_amdgcn_wave_barrier();
        }
        #pragma unroll
        for (int o = 1; o < 16; o <<= 1) lsum += __shfl_xor(lsum, o, 64);
        denom = lsum;
    }

    float inv = 1.f / (denom + 1e-16f);
    float4 b4 = *(const float4*)(bias + (qlane << 2));
    acc.x = acc.x * inv + b4.x;
    acc.y = acc.y * inv + b4.y;
    acc.z = acc.z * inv + b4.z;
    acc.w = acc.w * inv + b4.w;
    if (do_relu) {
        acc.x = fmaxf(acc.x, 0.f); acc.y = fmaxf(acc.y, 0.f);
        acc.z = fmaxf(acc.z, 0.f); acc.w = fmaxf(acc.w, 0.f);
    }
    *(float4*)(Out + (size_t)n * HID + (qlane << 2)) = acc;
}

// ---- mean pool (batch sorted) ----
__global__ void pool_k(const float* __restrict__ act, const int* __restrict__ batch,
                       float* __restrict__ sums, float* __restrict__ cnt) {
    const int CHUNK = 16;
    int wv = threadIdx.x >> 6, lane = threadIdx.x & 63;
    int wid = blockIdx.x * 4 + wv;
    int base = wid * CHUNK;
    if (base >= N_NODES) return;
    int end = min(base + CHUNK, N_NODES);
    int g0 = batch[base], g1 = batch[end - 1];
    if (g0 == g1) {
        float acc = 0.f;
        int n = base;
        for (; n + 4 <= end; n += 4) {
            float v0 = act[(size_t)n * HID + lane];
            float v1 = act[(size_t)(n + 1) * HID + lane];
            float v2 = act[(size_t)(n + 2) * HID + lane];
            float v3 = act[(size_t)(n + 3) * HID + lane];
            acc += v0 + v1 + v2 + v3;
        }
        for (; n < end; ++n) acc += act[(size_t)n * HID + lane];
        atomicAdd(&sums[(size_t)g0 * HID + lane], acc);
        if (lane == 0) atomicAdd(&cnt[g0], (float)(end - base));
    } else {
        float acc = 0.f;
        int cur = g0, cl = 0;
        for (int n = base; n < end; ++n) {
            int g = batch[n];
            if (g != cur) {
                atomicAdd(&sums[(size_t)cur * HID + lane], acc);
                if (lane == 0) atomicAdd(&cnt[cur], (float)cl);
                acc = 0.f; cl = 0; cur = g;
            }
            acc += act[(size_t)n * HID + lane];
            cl++;
        }
        atomicAdd(&sums[(size_t)cur * HID + lane], acc);
        if (lane == 0) atomicAdd(&cnt[cur], (float)cl);
    }
}

// ---- readout: mean, linear, sigmoid ----
__global__ void readout_k(const float* __restrict__ sums, const float* __restrict__ cnt,
                          const float* __restrict__ lin_w, const float* __restrict__ lin_b,
                          float* __restrict__ out) {
    int wv = threadIdx.x >> 6, lane = threadIdx.x & 63;
    int g = blockIdx.x * 4 + wv;
    if (g >= NG) return;
    float c = fmaxf(cnt[g], 1.f);
    float v = sums[(size_t)g * HID + lane] / c * lin_w[lane];
    v = wave_sum(v);
    if (lane == 0) {
        float z = v + lin_b[0];
        out[g] = 1.f / (1.f + __expf(-z));
    }
}

extern "C" void kernel_launch(void* const* d_in, const int* in_sizes, int n_in,
                              void* d_out, int out_size, void* d_ws, size_t ws_size,
                              hipStream_t stream) {
    const float* x     = (const float*)d_in[0];
    const int*   ei    = (const int*)d_in[1];
    const float* ew    = (const float*)d_in[2];
    const int*   batch = (const int*)d_in[3];
    const float* W1  = (const float*)d_in[4];
    const float* as1 = (const float*)d_in[5];
    const float* ad1 = (const float*)d_in[6];
    const float* We1 = (const float*)d_in[7];
    const float* ae1 = (const float*)d_in[8];
    const float* b1  = (const float*)d_in[9];
    const float* W2  = (const float*)d_in[10];
    const float* as2 = (const float*)d_in[11];
    const float* ad2 = (const float*)d_in[12];
    const float* We2 = (const float*)d_in[13];
    const float* ae2 = (const float*)d_in[14];
    const float* b2  = (const float*)d_in[15];
    const float* W3  = (const float*)d_in[16];
    const float* as3 = (const float*)d_in[17];
    const float* ad3 = (const float*)d_in[18];
    const float* We3 = (const float*)d_in[19];
    const float* ae3 = (const float*)d_in[20];
    const float* b3  = (const float*)d_in[21];
    const float* lin_w = (const float*)d_in[22];
    const float* lin_b = (const float*)d_in[23];
    float* out = (float*)d_out;

    char* w = (char*)d_ws;
    size_t off = 0;
    auto alloc = [&](size_t bytes) -> void* {
        void* p = w + off;
        off = (off + bytes + 255) & ~(size_t)255;
        return p;
    };
    // zeroed region (memset each call; ws is poisoned)
    int*   counts   = (int*)alloc(N_NODES * sizeof(int));
    float* mean_acc = (float*)alloc(sizeof(float));
    float* cnt_g    = (float*)alloc(NG * sizeof(float));
    float* sums_g   = (float*)alloc((size_t)NG * HID * sizeof(float));
    size_t zero_bytes = off;
    // non-zeroed
    float* ce      = (float*)alloc(4 * sizeof(float));
    int*   row_ptr = (int*)alloc((N_NODES + 1) * sizeof(int));
    int*   fill    = (int*)alloc(N_NODES * sizeof(int));
    int*   bsums   = (int*)alloc(64 * sizeof(int));
    unsigned* csr  = (unsigned*)alloc((size_t)ET * sizeof(unsigned));
    float* a_src   = (float*)alloc(N_NODES * sizeof(float));
    float* a_dst   = (float*)alloc(N_NODES * sizeof(float));
    unsigned short* hbuf = (unsigned short*)alloc((size_t)N_NODES * HID * sizeof(unsigned short));
    float* actA    = (float*)alloc((size_t)N_NODES * HID * sizeof(float));
    float* actB    = (float*)alloc((size_t)N_NODES * HID * sizeof(float));

    hipMemsetAsync(d_ws, 0, zero_bytes, stream);

    int xgrid = ((ET + EPB - 1) / EPB) * 8;
    edge_prep_k<<<xgrid, 256, 0, stream>>>(ei, ew, counts, mean_acc,
                                           We1, ae1, We2, ae2, We3, ae3, ce);
    int sgrid = (N_NODES + 1023) / 1024;  // 49
    scan1_k<<<sgrid, 1024, 0, stream>>>(counts, row_ptr, bsums);
    scan3_k<<<sgrid, 1024, 0, stream>>>(counts, row_ptr, bsums, fill, sgrid);
    scatter_k<<<xgrid, 256, 0, stream>>>(ei, ew, mean_acc, fill, csr);

    int ggrid = (N_NODES + 63) / 64;
    int agrid = (N_NODES + 15) / 16;

    size_t lds1 = (size_t)(F_IN_DIM * HID + 64 * 17) * sizeof(float);
    size_t lds2 = (size_t)(HID * HID + 64 * 17) * sizeof(float);

    // layer 1
    gemm_att_k<<<ggrid, 256, lds1, stream>>>(x, F_IN_DIM, W1, as1, ad1, hbuf, a_src, a_dst);
    aggregate_k<<<agrid, 256, 0, stream>>>(hbuf, row_ptr, csr, a_src, a_dst, ce, 0, b1, actA, 1);
    // layer 2
    gemm_att_k<<<ggrid, 256, lds2, stream>>>(actA, HID, W2, as2, ad2, hbuf, a_src, a_dst);
    aggregate_k<<<agrid, 256, 0, stream>>>(hbuf, row_ptr, csr, a_src, a_dst, ce, 1, b2, actB, 1);
    // layer 3
    gemm_att_k<<<ggrid, 256, lds2, stream>>>(actB, HID, W3, as3, ad3, hbuf, a_src, a_dst);
    aggregate_k<<<agrid, 256, 0, stream>>>(hbuf, row_ptr, csr, a_src, a_dst, ce, 2, b3, actA, 0);

    // pool + readout
    int pgrid = ((N_NODES + 15) / 16 + 3) / 4;
    pool_k<<<pgrid, 256, 0, stream>>>(actA, batch, sums_g, cnt_g);
    readout_k<<<NG / 4, 256, 0, stream>>>(sums_g, cnt_g, lin_w, lin_b, out);
}